// Round 14
// baseline (332.677 us; speedup 1.0000x reference)
//
#include <hip/hip_runtime.h>
#include <hip/hip_bf16.h>

typedef float f32x2 __attribute__((ext_vector_type(2)));

#define SFP 36                     // u32 stride for packed tables
#define SAP 40                     // u16 stride for packed u tile
#define SB 34                      // f32x2 stride for f32 data buffers
#define KIDX(i) ((i) + ((i) >> 5)) // +1-per-32 padded f32 k-row addressing
#define W32A 0.19634954084936207f  // 2*pi/32
#define W1KA 0.006135923151542565f // 2*pi/1024
#define SC1K 0.0009765625f         // 2^-10 (exact)

__device__ __forceinline__ unsigned short f2bf(float x) {
    union { __hip_bfloat16 h; unsigned short u; } cv;
    cv.h = __float2bfloat16(x);
    return cv.u;
}
__device__ __forceinline__ float bfb2f(unsigned short b) {
    union { unsigned int u; float f; } cv;
    cv.u = ((unsigned int)b) << 16;
    return cv.f;
}
__device__ __forceinline__ unsigned int pk2(float re, float im) {
    return (unsigned int)f2bf(re) | ((unsigned int)f2bf(im) << 16);
}
__device__ __forceinline__ f32x2 upk(unsigned int p) {
    union { unsigned int u; float f; } a, b;
    a.u = p << 16;
    b.u = p & 0xFFFF0000u;
    return (f32x2){a.f, b.f};
}
__device__ __forceinline__ f32x2 cmul2(f32x2 a, f32x2 b) {
    return (f32x2){a.x*b.x - a.y*b.y, a.x*b.y + a.y*b.x};
}
#define VFMA(a, b, c) __builtin_elementwise_fma((f32x2)(a), (f32x2)(b), (f32x2)(c))

__global__ __launch_bounds__(256, 4) void tkmon4(
    const float* __restrict__ U, const float* __restrict__ K,
    float* __restrict__ OUT)
{
    __shared__ unsigned int cFp[32*SFP];       // packed F ; Finv = conj(F)
    __shared__ unsigned int cTwip[32*SFP];     // packed twinv ; tw = conj(twinv)*2^-10
    __shared__ unsigned int cKfp[32*SFP];      // packed kfT: [i][j] = k_hat[i+32j]
    __shared__ unsigned short aAp[2][32*SAP];  // double-buffered bf16 u tile
    __shared__ f32x2 b1[32*SB];                // f32 stage buffer (X1tw, then Z)
    __shared__ f32x2 b2[32*SB];                // f32 stage buffer (Y); hosts sk pre-loop

    const int t   = threadIdx.x;
    const int h   = blockIdx.x >> 1;
    const int it0 = (blockIdx.x & 1) << 3;     // 8 b-tiles per block
    const int r   = t >> 3;                    // owned row 0..31
    const int c0  = (t & 7) << 2;              // owned cols c0..c0+3

    float* sk = reinterpret_cast<float*>(b2);  // k row (padded), dead after kfft

    // ---- load k row + generate packed twiddle tables ----
    #pragma unroll
    for (int s = 0; s < 4; ++s) {
        int i = t + 256*s;
        sk[KIDX(i)] = K[(size_t)h*1024 + i];
    }
    #pragma unroll
    for (int ii = 0; ii < 4; ++ii) {
        int idx = 4*t + ii;
        int rr = idx >> 5, cc = idx & 31;
        int m32 = (rr * cc) & 31;
        float s32, c32; sincosf((float)m32 * W32A, &s32, &c32);
        cFp[rr*SFP + cc] = pk2(c32, -s32);
        int m1k = (rr * cc) & 1023;
        float s1k, c1k; sincosf((float)m1k * W1KA, &s1k, &c1k);
        cTwip[rr*SFP + cc] = pk2(c1k, s1k);
    }
    __syncthreads();

    // ---- in-block 1024-pt k-FFT (2-stage CT, f32): cKfp[i][j] = pack(k_hat[i+32j]) ----
    {
        f32x2* cT = b1;    // scratch
        const int i0 = t >> 3, q0 = (t & 7) << 2;
        float si, ci;
        sincosf(W32A * (float)i0, &si, &ci);
        const f32x2 stepi = {ci, -si};
        #pragma unroll
        for (int cc = q0; cc < q0 + 4; ++cc) {
            f32x2 wv = {1.f, 0.f}, acc = {0.f, 0.f};
            for (int rr = 0; rr < 32; ++rr) {
                float kv = sk[KIDX(32*rr + cc)];
                acc = VFMA(((f32x2){kv, kv}), wv, acc);
                wv = cmul2(wv, stepi);
            }
            float sp, cp;
            sincosf(W1KA * (float)(i0 * cc), &sp, &cp);
            cT[i0*SB + cc] = cmul2(acc, (f32x2){cp, -sp});
        }
        __syncthreads();
        #pragma unroll
        for (int j = q0; j < q0 + 4; ++j) {
            float sj, cj;
            sincosf(W32A * (float)j, &sj, &cj);
            const f32x2 stepj = {cj, -sj};
            f32x2 wv = {1.f, 0.f}, acc = {0.f, 0.f};
            for (int cc = 0; cc < 32; ++cc) {
                f32x2 tv = cT[i0*SB + cc];
                acc = VFMA(((f32x2){tv.x, tv.x}), wv, acc);
                acc = VFMA(((f32x2){-tv.y, tv.y}), ((f32x2){wv.y, wv.x}), acc);
                wv = cmul2(wv, stepj);
            }
            cKfp[i0*SFP + j] = pk2(acc.x, acc.y);
        }
    }
    // prologue: stage first tile into aAp[0]
    {
        float4 uv = *reinterpret_cast<const float4*>(U + ((size_t)it0 * 1024 + h) * 1024 + 4*t);
        ushort4 av;
        av.x = f2bf(uv.x); av.y = f2bf(uv.y); av.z = f2bf(uv.z); av.w = f2bf(uv.w);
        *reinterpret_cast<ushort4*>(&aAp[0][r*SAP + c0]) = av;
    }

    // ==== 8 batch tiles, 2 barriers per tile ====
    for (int ii = 0; ii < 8; ++ii) {
        const int it = it0 + ii;
        const int cur = ii & 1;
        const size_t base = ((size_t)it * 1024 + h) * 1024;

        __syncthreads();   // barrier A: aAp[cur] complete; b1 free (S4 readers done)

        // S1: X1[i][c] = sum_j F[i][j]*A[j][c] ; * tw ; -> b1 (own rows; wave-private dep)
        {
            f32x2 A0={0,0}, A1={0,0}, A2={0,0}, A3={0,0};
            #pragma unroll 16
            for (int j = 0; j < 32; ++j) {
                f32x2 fv = upk(cFp[r*SFP + j]);
                ushort4 a4 = *reinterpret_cast<const ushort4*>(&aAp[cur][j*SAP + c0]);
                float v0 = bfb2f(a4.x), v1 = bfb2f(a4.y), v2 = bfb2f(a4.z), v3 = bfb2f(a4.w);
                A0 = VFMA(fv, ((f32x2){v0, v0}), A0);
                A1 = VFMA(fv, ((f32x2){v1, v1}), A1);
                A2 = VFMA(fv, ((f32x2){v2, v2}), A2);
                A3 = VFMA(fv, ((f32x2){v3, v3}), A3);
            }
            uint4 w4 = *reinterpret_cast<const uint4*>(&cTwip[r*SFP + c0]);
            f32x2 w0 = upk(w4.x), w1 = upk(w4.y), w2 = upk(w4.z), w3 = upk(w4.w);
            f32x2 x0 = cmul2(A0, (f32x2){w0.x*SC1K, -w0.y*SC1K});
            f32x2 x1 = cmul2(A1, (f32x2){w1.x*SC1K, -w1.y*SC1K});
            f32x2 x2 = cmul2(A2, (f32x2){w2.x*SC1K, -w2.y*SC1K});
            f32x2 x3 = cmul2(A3, (f32x2){w3.x*SC1K, -w3.y*SC1K});
            *reinterpret_cast<float4*>(&b1[r*SB + c0    ]) = make_float4(x0.x, x0.y, x1.x, x1.y);
            *reinterpret_cast<float4*>(&b1[r*SB + c0 + 2]) = make_float4(x2.x, x2.y, x3.x, x3.y);
        }

        // prefetch next tile (latency hidden under S2+S3)
        float4 pv;
        if (ii < 7) {
            const size_t nbase = ((size_t)(it + 1) * 1024 + h) * 1024;
            pv = *reinterpret_cast<const float4*>(U + nbase + 4*t);
        }

        // S2: X2[i][m] = sum_c X1tw[i][c]*F[c][m] ; * kf ; -> b2 (own rows)
        {
            f32x2 A0={0,0}, A1={0,0}, A2={0,0}, A3={0,0};
            #pragma unroll 16
            for (int c = 0; c < 32; ++c) {
                f32x2 xv = b1[r*SB + c];          // own-row broadcast (wave-private)
                f32x2 xl = {xv.x, xv.x};
                f32x2 xh = {-xv.y, xv.y};
                uint4 f4 = *reinterpret_cast<const uint4*>(&cFp[c*SFP + c0]);
                f32x2 y0 = upk(f4.x), y1 = upk(f4.y), y2 = upk(f4.z), y3 = upk(f4.w);
                A0 = VFMA(xl, y0, A0); A0 = VFMA(xh, ((f32x2){y0.y, y0.x}), A0);
                A1 = VFMA(xl, y1, A1); A1 = VFMA(xh, ((f32x2){y1.y, y1.x}), A1);
                A2 = VFMA(xl, y2, A2); A2 = VFMA(xh, ((f32x2){y2.y, y2.x}), A2);
                A3 = VFMA(xl, y3, A3); A3 = VFMA(xh, ((f32x2){y3.y, y3.x}), A3);
            }
            uint4 k4 = *reinterpret_cast<const uint4*>(&cKfp[r*SFP + c0]);
            f32x2 z0 = cmul2(A0, upk(k4.x));
            f32x2 z1 = cmul2(A1, upk(k4.y));
            f32x2 z2 = cmul2(A2, upk(k4.z));
            f32x2 z3 = cmul2(A3, upk(k4.w));
            *reinterpret_cast<float4*>(&b2[r*SB + c0    ]) = make_float4(z0.x, z0.y, z1.x, z1.y);
            *reinterpret_cast<float4*>(&b2[r*SB + c0 + 2]) = make_float4(z2.x, z2.y, z3.x, z3.y);
        }

        // S3: W[i][p] = sum_m Y[i][m]*conj(F[m][p]) ; * twinv ; -> b1 (own rows)
        {
            f32x2 A0={0,0}, A1={0,0}, A2={0,0}, A3={0,0};
            #pragma unroll 16
            for (int m = 0; m < 32; ++m) {
                f32x2 yv = b2[r*SB + m];          // own-row broadcast (wave-private)
                f32x2 yc = {yv.y, -yv.x};
                uint4 g4 = *reinterpret_cast<const uint4*>(&cFp[m*SFP + c0]);
                f32x2 g0 = upk(g4.x), g1 = upk(g4.y), g2 = upk(g4.z), g3 = upk(g4.w);
                A0 = VFMA(yv, ((f32x2){g0.x, g0.x}), A0); A0 = VFMA(yc, ((f32x2){g0.y, g0.y}), A0);
                A1 = VFMA(yv, ((f32x2){g1.x, g1.x}), A1); A1 = VFMA(yc, ((f32x2){g1.y, g1.y}), A1);
                A2 = VFMA(yv, ((f32x2){g2.x, g2.x}), A2); A2 = VFMA(yc, ((f32x2){g2.y, g2.y}), A2);
                A3 = VFMA(yv, ((f32x2){g3.x, g3.x}), A3); A3 = VFMA(yc, ((f32x2){g3.y, g3.y}), A3);
            }
            uint4 w4 = *reinterpret_cast<const uint4*>(&cTwip[r*SFP + c0]);
            f32x2 z0 = cmul2(A0, upk(w4.x));
            f32x2 z1 = cmul2(A1, upk(w4.y));
            f32x2 z2 = cmul2(A2, upk(w4.z));
            f32x2 z3 = cmul2(A3, upk(w4.w));
            *reinterpret_cast<float4*>(&b1[r*SB + c0    ]) = make_float4(z0.x, z0.y, z1.x, z1.y);
            *reinterpret_cast<float4*>(&b1[r*SB + c0 + 2]) = make_float4(z2.x, z2.y, z3.x, z3.y);
        }

        __syncthreads();   // barrier B: all Z rows in b1 ready

        // write next tile's aAp (other buffer; readers of aAp[cur] all finished S1)
        if (ii < 7) {
            ushort4 av;
            av.x = f2bf(pv.x); av.y = f2bf(pv.y); av.z = f2bf(pv.z); av.w = f2bf(pv.w);
            *reinterpret_cast<ushort4*>(&aAp[cur ^ 1][r*SAP + c0]) = av;
        }

        // S4: O[q][p] = Re( sum_i conj(F[q][i])*Z[i][p] ) ; coalesced store
        {
            f32x2 O0={0,0}, O1={0,0}, O2={0,0}, O3={0,0};
            #pragma unroll 16
            for (int i = 0; i < 32; ++i) {
                f32x2 gv = upk(cFp[r*SFP + i]);
                float4 p01 = *reinterpret_cast<const float4*>(&b1[i*SB + c0]);
                float4 p23 = *reinterpret_cast<const float4*>(&b1[i*SB + c0 + 2]);
                O0 = VFMA(gv, ((f32x2){p01.x, p01.y}), O0);
                O1 = VFMA(gv, ((f32x2){p01.z, p01.w}), O1);
                O2 = VFMA(gv, ((f32x2){p23.x, p23.y}), O2);
                O3 = VFMA(gv, ((f32x2){p23.z, p23.w}), O3);
            }
            *reinterpret_cast<float4*>(OUT + base + 4*t) =
                make_float4(O0.x + O0.y, O1.x + O1.y, O2.x + O2.y, O3.x + O3.y);
        }
    }
}

extern "C" void kernel_launch(void* const* d_in, const int* in_sizes, int n_in,
                              void* d_out, int out_size, void* d_ws, size_t ws_size,
                              hipStream_t stream) {
    const float* U = (const float*)d_in[0];
    const float* K = (const float*)d_in[1];
    float* OUT = (float*)d_out;

    tkmon4<<<dim3(2048), dim3(256), 0, stream>>>(U, K, OUT);
}

// Round 15
// 202.761 us; speedup vs baseline: 1.6407x; 1.6407x over previous
//
#include <hip/hip_runtime.h>
#include <hip/hip_bf16.h>

#define ST 36                      // u32 stride for packed tables/A (144 B rows, 16B-aligned)
#define SB 34                      // float2 stride for f32 buffers (272 B rows, 16B-aligned)
#define KIDX(i) ((i) + ((i) >> 5)) // +1-per-32 padded f32 k-row addressing
#define W32A 0.19634954084936207f  // 2*pi/32
#define W1KA 0.006135923151542565f // 2*pi/1024
#define SC1K 0.0009765625f         // 2^-10 (exact)

__device__ __forceinline__ unsigned short f2bf(float x) {
    union { __hip_bfloat16 h; unsigned short u; } cv;
    cv.h = __float2bfloat16(x);
    return cv.u;
}
__device__ __forceinline__ float bfb2f(unsigned short b) {
    union { unsigned int u; float f; } cv;
    cv.u = ((unsigned int)b) << 16;
    return cv.f;
}
__device__ __forceinline__ unsigned int pk2(float re, float im) {
    return (unsigned int)f2bf(re) | ((unsigned int)f2bf(im) << 16);
}
__device__ __forceinline__ float2 upk(unsigned int p) {
    union { unsigned int u; float f; } a, b;
    a.u = p << 16;
    b.u = p & 0xFFFF0000u;
    return make_float2(a.f, b.f);
}
__device__ __forceinline__ float2 cmul2(float2 a, float2 b) {
    return make_float2(a.x*b.x - a.y*b.y, a.x*b.y + a.y*b.x);
}
// a += x*y
__device__ __forceinline__ void cmac2(float2& a, float2 x, float2 y) {
    a.x = fmaf(x.x, y.x, fmaf(-x.y, y.y, a.x));
    a.y = fmaf(x.x, y.y, fmaf( x.y, y.x, a.y));
}
// a += x*conj(y)
__device__ __forceinline__ void cmacC(float2& a, float2 x, float2 y) {
    a.x = fmaf(x.x, y.x, fmaf( x.y, y.y, a.x));
    a.y = fmaf(x.y, y.x, fmaf(-x.x, y.y, a.y));
}

__global__ __launch_bounds__(256) void tkmon5(
    const float* __restrict__ U, const float* __restrict__ K,
    float* __restrict__ OUT)
{
    __shared__ unsigned int cFp[32*ST];     // packed F ; Finv = conj(F) via fma signs
    __shared__ unsigned int cTwip[32*ST];   // packed twinv ; tw = conj(twinv)*2^-10
    __shared__ unsigned int cKfp[32*ST];    // packed kfT: [i][j] = k_hat[i+32j]
    __shared__ unsigned int aAp[2][32*ST];  // double-buffered packed complex u pair
    __shared__ float2 b1[32*SB];            // f32 stage buffer (X1tw, then Z); CT scratch
    __shared__ float2 b2[32*SB];            // f32 stage buffer (Y); hosts sk pre-loop

    const int t  = threadIdx.x;
    const int h  = blockIdx.x >> 1;
    const int p0 = (blockIdx.x & 1) << 2;   // first pass; each pass = 2 b-tiles
    const int r  = t >> 3;                  // owned row 0..31
    const int c0 = (t & 7) << 2;            // owned cols c0..c0+3

    float* sk = reinterpret_cast<float*>(b2);   // k row (padded), dead after kfft

    // ---- load k row + generate packed twiddle tables ----
    #pragma unroll
    for (int s = 0; s < 4; ++s) {
        int i = t + 256*s;
        sk[KIDX(i)] = K[(size_t)h*1024 + i];
    }
    #pragma unroll
    for (int ii = 0; ii < 4; ++ii) {
        int idx = 4*t + ii;
        int rr = idx >> 5, cc = idx & 31;
        int m32 = (rr * cc) & 31;
        float s32, c32; sincosf((float)m32 * W32A, &s32, &c32);
        cFp[rr*ST + cc] = pk2(c32, -s32);
        int m1k = (rr * cc) & 1023;
        float s1k, c1k; sincosf((float)m1k * W1KA, &s1k, &c1k);
        cTwip[rr*ST + cc] = pk2(c1k, s1k);
    }
    __syncthreads();

    // ---- in-block 1024-pt k-FFT (2-stage CT, f32): cKfp[i][j] = pack(k_hat[i+32j]) ----
    {
        float2* cT = b1;    // scratch
        const int i0 = t >> 3, q0 = (t & 7) << 2;
        float si, ci;
        sincosf(W32A * (float)i0, &si, &ci);
        const float2 stepi = make_float2(ci, -si);
        #pragma unroll
        for (int cc = q0; cc < q0 + 4; ++cc) {
            float2 wv = make_float2(1.f, 0.f), acc = make_float2(0.f, 0.f);
            for (int rr = 0; rr < 32; ++rr) {
                float kv = sk[KIDX(32*rr + cc)];
                acc.x = fmaf(kv, wv.x, acc.x);
                acc.y = fmaf(kv, wv.y, acc.y);
                wv = cmul2(wv, stepi);
            }
            float sp, cp;
            sincosf(W1KA * (float)(i0 * cc), &sp, &cp);
            cT[i0*SB + cc] = cmul2(acc, make_float2(cp, -sp));
        }
        __syncthreads();
        #pragma unroll
        for (int j = q0; j < q0 + 4; ++j) {
            float sj, cj;
            sincosf(W32A * (float)j, &sj, &cj);
            const float2 stepj = make_float2(cj, -sj);
            float2 wv = make_float2(1.f, 0.f), acc = make_float2(0.f, 0.f);
            for (int cc = 0; cc < 32; ++cc) {
                float2 tv = cT[i0*SB + cc];
                acc.x = fmaf(tv.x, wv.x, fmaf(-tv.y, wv.y, acc.x));
                acc.y = fmaf(tv.x, wv.y, fmaf( tv.y, wv.x, acc.y));
                wv = cmul2(wv, stepj);
            }
            cKfp[i0*ST + j] = pk2(acc.x, acc.y);
        }
    }

    // ---- prologue: stage first pass pair (tiles 2p0, 2p0+1) packed into aAp[0] ----
    {
        const size_t be = ((size_t)(2*p0) * 1024 + h) * 1024;
        float4 ue = *reinterpret_cast<const float4*>(U + be + 4*t);
        float4 uo = *reinterpret_cast<const float4*>(U + be + 1048576 + 4*t);
        uint4 av;
        av.x = pk2(ue.x, uo.x); av.y = pk2(ue.y, uo.y);
        av.z = pk2(ue.z, uo.z); av.w = pk2(ue.w, uo.w);
        *reinterpret_cast<uint4*>(&aAp[0][r*ST + c0]) = av;
    }

    // ==== 4 passes (2 b-tiles each), 2 barriers per pass ====
    for (int ii = 0; ii < 4; ++ii) {
        const int pass = p0 + ii;
        const int cur  = ii & 1;
        const size_t be = ((size_t)(2*pass) * 1024 + h) * 1024;

        __syncthreads();   // barrier A: aAp[cur] visible; b1 free (prev S4 / kfft done)

        // S1: X1[i][c] = sum_j F[i][j]*Z[j][c] ; * tw (= conj(twinv)*2^-10) ; -> b1
        {
            float2 A0={0,0}, A1={0,0}, A2={0,0}, A3={0,0};
            #pragma unroll 16
            for (int j = 0; j < 32; ++j) {
                float2 fv = upk(cFp[r*ST + j]);
                uint4 a4 = *reinterpret_cast<const uint4*>(&aAp[cur][j*ST + c0]);
                cmac2(A0, fv, upk(a4.x));
                cmac2(A1, fv, upk(a4.y));
                cmac2(A2, fv, upk(a4.z));
                cmac2(A3, fv, upk(a4.w));
            }
            uint4 w4 = *reinterpret_cast<const uint4*>(&cTwip[r*ST + c0]);
            float2 w0 = upk(w4.x), w1 = upk(w4.y), w2 = upk(w4.z), w3 = upk(w4.w);
            float2 x0 = cmul2(A0, make_float2(w0.x*SC1K, -w0.y*SC1K));
            float2 x1 = cmul2(A1, make_float2(w1.x*SC1K, -w1.y*SC1K));
            float2 x2 = cmul2(A2, make_float2(w2.x*SC1K, -w2.y*SC1K));
            float2 x3 = cmul2(A3, make_float2(w3.x*SC1K, -w3.y*SC1K));
            *reinterpret_cast<float4*>(&b1[r*SB + c0    ]) = make_float4(x0.x, x0.y, x1.x, x1.y);
            *reinterpret_cast<float4*>(&b1[r*SB + c0 + 2]) = make_float4(x2.x, x2.y, x3.x, x3.y);
        }

        // prefetch next pass's pair (latency hidden under S2+S3)
        float4 pe, po;
        if (ii < 3) {
            const size_t nb = ((size_t)(2*pass + 2) * 1024 + h) * 1024;
            pe = *reinterpret_cast<const float4*>(U + nb + 4*t);
            po = *reinterpret_cast<const float4*>(U + nb + 1048576 + 4*t);
        }

        // S2: X2[i][m] = sum_c X1tw[i][c]*F[c][m] ; * kf ; -> b2 (own rows, wave-private)
        {
            float2 A0={0,0}, A1={0,0}, A2={0,0}, A3={0,0};
            #pragma unroll 16
            for (int c = 0; c < 32; ++c) {
                float2 xv = b1[r*SB + c];
                uint4 f4 = *reinterpret_cast<const uint4*>(&cFp[c*ST + c0]);
                cmac2(A0, xv, upk(f4.x));
                cmac2(A1, xv, upk(f4.y));
                cmac2(A2, xv, upk(f4.z));
                cmac2(A3, xv, upk(f4.w));
            }
            uint4 k4 = *reinterpret_cast<const uint4*>(&cKfp[r*ST + c0]);
            float2 y0 = cmul2(A0, upk(k4.x));
            float2 y1 = cmul2(A1, upk(k4.y));
            float2 y2 = cmul2(A2, upk(k4.z));
            float2 y3 = cmul2(A3, upk(k4.w));
            *reinterpret_cast<float4*>(&b2[r*SB + c0    ]) = make_float4(y0.x, y0.y, y1.x, y1.y);
            *reinterpret_cast<float4*>(&b2[r*SB + c0 + 2]) = make_float4(y2.x, y2.y, y3.x, y3.y);
        }

        // S3: W[i][p] = sum_m Y[i][m]*conj(F[m][p]) ; * twinv ; -> b1 (own rows)
        {
            float2 A0={0,0}, A1={0,0}, A2={0,0}, A3={0,0};
            #pragma unroll 16
            for (int m = 0; m < 32; ++m) {
                float2 yv = b2[r*SB + m];
                uint4 g4 = *reinterpret_cast<const uint4*>(&cFp[m*ST + c0]);
                cmacC(A0, yv, upk(g4.x));
                cmacC(A1, yv, upk(g4.y));
                cmacC(A2, yv, upk(g4.z));
                cmacC(A3, yv, upk(g4.w));
            }
            uint4 w4 = *reinterpret_cast<const uint4*>(&cTwip[r*ST + c0]);
            float2 z0 = cmul2(A0, upk(w4.x));
            float2 z1 = cmul2(A1, upk(w4.y));
            float2 z2 = cmul2(A2, upk(w4.z));
            float2 z3 = cmul2(A3, upk(w4.w));
            *reinterpret_cast<float4*>(&b1[r*SB + c0    ]) = make_float4(z0.x, z0.y, z1.x, z1.y);
            *reinterpret_cast<float4*>(&b1[r*SB + c0 + 2]) = make_float4(z2.x, z2.y, z3.x, z3.y);
        }

        __syncthreads();   // barrier B: all Z rows ready; all aAp[cur] reads done

        // stage next pair into the other buffer
        if (ii < 3) {
            uint4 av;
            av.x = pk2(pe.x, po.x); av.y = pk2(pe.y, po.y);
            av.z = pk2(pe.z, po.z); av.w = pk2(pe.w, po.w);
            *reinterpret_cast<uint4*>(&aAp[cur ^ 1][r*ST + c0]) = av;
        }

        // S4: O[q][p] = sum_i conj(F[q][i])*Z[i][p] ; Re -> tile 2p, Im -> tile 2p+1
        {
            float2 O0={0,0}, O1={0,0}, O2={0,0}, O3={0,0};
            #pragma unroll 16
            for (int i = 0; i < 32; ++i) {
                float2 gv = upk(cFp[r*ST + i]);
                float4 p01 = *reinterpret_cast<const float4*>(&b1[i*SB + c0]);
                float4 p23 = *reinterpret_cast<const float4*>(&b1[i*SB + c0 + 2]);
                cmacC(O0, make_float2(p01.x, p01.y), gv);
                cmacC(O1, make_float2(p01.z, p01.w), gv);
                cmacC(O2, make_float2(p23.x, p23.y), gv);
                cmacC(O3, make_float2(p23.z, p23.w), gv);
            }
            *reinterpret_cast<float4*>(OUT + be + 4*t) =
                make_float4(O0.x, O1.x, O2.x, O3.x);
            *reinterpret_cast<float4*>(OUT + be + 1048576 + 4*t) =
                make_float4(O0.y, O1.y, O2.y, O3.y);
        }
    }
}

extern "C" void kernel_launch(void* const* d_in, const int* in_sizes, int n_in,
                              void* d_out, int out_size, void* d_ws, size_t ws_size,
                              hipStream_t stream) {
    const float* U = (const float*)d_in[0];
    const float* K = (const float*)d_in[1];
    float* OUT = (float*)d_out;

    tkmon5<<<dim3(2048), dim3(256), 0, stream>>>(U, K, OUT);
}

// Round 16
// 162.561 us; speedup vs baseline: 2.0465x; 1.2473x over previous
//
#include <hip/hip_runtime.h>
#include <hip/hip_bf16.h>

typedef float f32x2 __attribute__((ext_vector_type(2)));

#define ST 36                      // u32 stride for packed tables/A (144 B rows)
#define SB 34                      // f32x2 stride for f32 buffers (272 B rows)
#define KIDX(i) ((i) + ((i) >> 5)) // +1-per-32 padded f32 k-row addressing
#define W32A 0.19634954084936207f  // 2*pi/32
#define W1KA 0.006135923151542565f // 2*pi/1024
#define SC1K 0.0009765625f         // 2^-10 (exact)

__device__ __forceinline__ unsigned short f2bf(float x) {
    union { __hip_bfloat16 h; unsigned short u; } cv;
    cv.h = __float2bfloat16(x);
    return cv.u;
}
__device__ __forceinline__ unsigned int pk2(float re, float im) {
    return (unsigned int)f2bf(re) | ((unsigned int)f2bf(im) << 16);
}
__device__ __forceinline__ f32x2 upk(unsigned int p) {
    union { unsigned int u; float f; } a, b;
    a.u = p << 16;
    b.u = p & 0xFFFF0000u;
    return (f32x2){a.f, b.f};
}
// complex a += x*y   (2 × v_pk_fma_f32)
__device__ __forceinline__ void vcmac(f32x2& a, f32x2 x, f32x2 y) {
    a = __builtin_elementwise_fma((f32x2){x.x, x.x}, y, a);
    a = __builtin_elementwise_fma((f32x2){-x.y, x.y}, (f32x2){y.y, y.x}, a);
}
// complex a += x*conj(y)
__device__ __forceinline__ void vcmacC(f32x2& a, f32x2 x, f32x2 y) {
    a = __builtin_elementwise_fma((f32x2){y.x, y.x}, x, a);
    a = __builtin_elementwise_fma((f32x2){x.y, -x.x}, (f32x2){y.y, y.y}, a);
}
__device__ __forceinline__ f32x2 vcmul(f32x2 x, f32x2 y) {
    f32x2 r = (f32x2){0.f, 0.f};
    vcmac(r, x, y);
    return r;
}
__device__ __forceinline__ float2 cmul2(float2 a, float2 b) {
    return make_float2(a.x*b.x - a.y*b.y, a.x*b.y + a.y*b.x);
}

// ---------- standalone per-h k-FFT (2-stage CT, f32): KF[h*1024+i*32+j]=pack(k_hat[i+32j]) ----------
__global__ __launch_bounds__(256) void kfft_pre6(const float* __restrict__ K,
                                                 unsigned int* __restrict__ KF)
{
    __shared__ float sk[1056];
    __shared__ float2 cT[32*SB];
    const int t = threadIdx.x, h = blockIdx.x;
    #pragma unroll
    for (int s = 0; s < 4; ++s) {
        int i = t + 256*s;
        sk[KIDX(i)] = K[(size_t)h*1024 + i];
    }
    __syncthreads();
    const int i0 = t >> 3, q0 = (t & 7) << 2;
    float si, ci;
    sincosf(W32A * (float)i0, &si, &ci);
    const float2 stepi = make_float2(ci, -si);
    #pragma unroll
    for (int cc = q0; cc < q0 + 4; ++cc) {
        float2 wv = make_float2(1.f, 0.f), acc = make_float2(0.f, 0.f);
        for (int rr = 0; rr < 32; ++rr) {
            float kv = sk[KIDX(32*rr + cc)];
            acc.x = fmaf(kv, wv.x, acc.x);
            acc.y = fmaf(kv, wv.y, acc.y);
            wv = cmul2(wv, stepi);
        }
        float sp, cp;
        sincosf(W1KA * (float)(i0 * cc), &sp, &cp);
        cT[i0*SB + cc] = cmul2(acc, make_float2(cp, -sp));
    }
    __syncthreads();
    #pragma unroll
    for (int j = q0; j < q0 + 4; ++j) {
        float sj, cj;
        sincosf(W32A * (float)j, &sj, &cj);
        const float2 stepj = make_float2(cj, -sj);
        float2 wv = make_float2(1.f, 0.f), acc = make_float2(0.f, 0.f);
        for (int cc = 0; cc < 32; ++cc) {
            float2 tv = cT[i0*SB + cc];
            acc.x = fmaf(tv.x, wv.x, fmaf(-tv.y, wv.y, acc.x));
            acc.y = fmaf(tv.x, wv.y, fmaf( tv.y, wv.x, acc.y));
            wv = cmul2(wv, stepj);
        }
        KF[(size_t)h*1024 + i0*32 + j] = pk2(acc.x, acc.y);
    }
}

// ---------- main fused monarch conv; PASSES pairs per block ----------
template<int PASSES, bool USEKF>
__global__ __launch_bounds__(256) void tkmon6(
    const float* __restrict__ U, const float* __restrict__ K,
    const unsigned int* __restrict__ KF, float* __restrict__ OUT)
{
    constexpr int SH = (PASSES == 2) ? 2 : 1;   // blocks per h = 8/PASSES
    __shared__ unsigned int cFp[32*ST];     // packed F ; Finv = conj(F)
    __shared__ unsigned int cTwip[32*ST];   // packed twinv ; tw = conj(twinv)*2^-10
    __shared__ unsigned int cKfp[32*ST];    // packed kfT
    __shared__ unsigned int aAp[2][32*ST];  // double-buffered packed complex u pair
    __shared__ f32x2 b1[32*SB];             // stage buffer (X1tw, then Z); CT scratch
    __shared__ f32x2 b2[32*SB];             // stage buffer (Y); hosts sk pre-loop

    const int t  = threadIdx.x;
    const int h  = blockIdx.x >> SH;
    const int p0 = (blockIdx.x & ((1 << SH) - 1)) * PASSES;
    const int r  = t >> 3;
    const int c0 = (t & 7) << 2;

    // ---- generate packed twiddle tables ----
    #pragma unroll
    for (int ii = 0; ii < 4; ++ii) {
        int idx = 4*t + ii;
        int rr = idx >> 5, cc = idx & 31;
        int m32 = (rr * cc) & 31;
        float s32, c32; sincosf((float)m32 * W32A, &s32, &c32);
        cFp[rr*ST + cc] = pk2(c32, -s32);
        int m1k = (rr * cc) & 1023;
        float s1k, c1k; sincosf((float)m1k * W1KA, &s1k, &c1k);
        cTwip[rr*ST + cc] = pk2(c1k, s1k);
    }

    if (USEKF) {
        // coalesced load of precomputed packed k_hat
        uint4 kv = *reinterpret_cast<const uint4*>(&KF[(size_t)h*1024 + 4*t]);
        *reinterpret_cast<uint4*>(&cKfp[r*ST + c0]) = kv;
    } else {
        // in-block k-FFT (r15-verified)
        float* sk = reinterpret_cast<float*>(b2);
        #pragma unroll
        for (int s = 0; s < 4; ++s) {
            int i = t + 256*s;
            sk[KIDX(i)] = K[(size_t)h*1024 + i];
        }
        __syncthreads();
        float2* cT = reinterpret_cast<float2*>(b1);
        const int i0 = t >> 3, q0 = (t & 7) << 2;
        float si, ci;
        sincosf(W32A * (float)i0, &si, &ci);
        const float2 stepi = make_float2(ci, -si);
        #pragma unroll
        for (int cc = q0; cc < q0 + 4; ++cc) {
            float2 wv = make_float2(1.f, 0.f), acc = make_float2(0.f, 0.f);
            for (int rr = 0; rr < 32; ++rr) {
                float kv = sk[KIDX(32*rr + cc)];
                acc.x = fmaf(kv, wv.x, acc.x);
                acc.y = fmaf(kv, wv.y, acc.y);
                wv = cmul2(wv, stepi);
            }
            float sp, cp;
            sincosf(W1KA * (float)(i0 * cc), &sp, &cp);
            cT[i0*SB + cc] = cmul2(acc, make_float2(cp, -sp));
        }
        __syncthreads();
        #pragma unroll
        for (int j = q0; j < q0 + 4; ++j) {
            float sj, cj;
            sincosf(W32A * (float)j, &sj, &cj);
            const float2 stepj = make_float2(cj, -sj);
            float2 wv = make_float2(1.f, 0.f), acc = make_float2(0.f, 0.f);
            for (int cc = 0; cc < 32; ++cc) {
                float2 tv = cT[i0*SB + cc];
                acc.x = fmaf(tv.x, wv.x, fmaf(-tv.y, wv.y, acc.x));
                acc.y = fmaf(tv.x, wv.y, fmaf( tv.y, wv.x, acc.y));
                wv = cmul2(wv, stepj);
            }
            cKfp[i0*ST + j] = pk2(acc.x, acc.y);
        }
    }

    // ---- prologue: stage first pass pair into aAp[0] ----
    {
        const size_t be = ((size_t)(2*p0) * 1024 + h) * 1024;
        float4 ue = *reinterpret_cast<const float4*>(U + be + 4*t);
        float4 uo = *reinterpret_cast<const float4*>(U + be + 1048576 + 4*t);
        uint4 av;
        av.x = pk2(ue.x, uo.x); av.y = pk2(ue.y, uo.y);
        av.z = pk2(ue.z, uo.z); av.w = pk2(ue.w, uo.w);
        *reinterpret_cast<uint4*>(&aAp[0][r*ST + c0]) = av;
    }

    const f32x2 scv = {SC1K, -SC1K};

    // ==== PASSES passes (2 b-tiles each), 2 barriers per pass ====
    for (int ii = 0; ii < PASSES; ++ii) {
        const int pass = p0 + ii;
        const int cur  = ii & 1;
        const size_t be = ((size_t)(2*pass) * 1024 + h) * 1024;

        __syncthreads();   // barrier A: aAp[cur] + tables/kf visible; b1 free

        // S1: X1[i][c] = sum_j F[i][j]*Z[j][c] ; * tw ; -> b1
        {
            f32x2 A0={0,0}, A1={0,0}, A2={0,0}, A3={0,0};
            #pragma unroll 16
            for (int j = 0; j < 32; ++j) {
                f32x2 fv = upk(cFp[r*ST + j]);
                uint4 a4 = *reinterpret_cast<const uint4*>(&aAp[cur][j*ST + c0]);
                vcmac(A0, fv, upk(a4.x));
                vcmac(A1, fv, upk(a4.y));
                vcmac(A2, fv, upk(a4.z));
                vcmac(A3, fv, upk(a4.w));
            }
            uint4 w4 = *reinterpret_cast<const uint4*>(&cTwip[r*ST + c0]);
            f32x2 x0 = vcmul(A0, upk(w4.x) * scv);
            f32x2 x1 = vcmul(A1, upk(w4.y) * scv);
            f32x2 x2 = vcmul(A2, upk(w4.z) * scv);
            f32x2 x3 = vcmul(A3, upk(w4.w) * scv);
            *reinterpret_cast<float4*>(&b1[r*SB + c0    ]) = make_float4(x0.x, x0.y, x1.x, x1.y);
            *reinterpret_cast<float4*>(&b1[r*SB + c0 + 2]) = make_float4(x2.x, x2.y, x3.x, x3.y);
        }

        // prefetch next pass's pair (latency hidden under S2+S3)
        float4 pe, po;
        if (ii < PASSES - 1) {
            const size_t nb = ((size_t)(2*pass + 2) * 1024 + h) * 1024;
            pe = *reinterpret_cast<const float4*>(U + nb + 4*t);
            po = *reinterpret_cast<const float4*>(U + nb + 1048576 + 4*t);
        }

        // S2: X2[i][m] = sum_c X1tw[i][c]*F[c][m] ; * kf ; -> b2 (own rows, wave-private)
        {
            f32x2 A0={0,0}, A1={0,0}, A2={0,0}, A3={0,0};
            #pragma unroll 16
            for (int c = 0; c < 32; ++c) {
                f32x2 xv = b1[r*SB + c];
                uint4 f4 = *reinterpret_cast<const uint4*>(&cFp[c*ST + c0]);
                vcmac(A0, xv, upk(f4.x));
                vcmac(A1, xv, upk(f4.y));
                vcmac(A2, xv, upk(f4.z));
                vcmac(A3, xv, upk(f4.w));
            }
            uint4 k4 = *reinterpret_cast<const uint4*>(&cKfp[r*ST + c0]);
            f32x2 y0 = vcmul(A0, upk(k4.x));
            f32x2 y1 = vcmul(A1, upk(k4.y));
            f32x2 y2 = vcmul(A2, upk(k4.z));
            f32x2 y3 = vcmul(A3, upk(k4.w));
            *reinterpret_cast<float4*>(&b2[r*SB + c0    ]) = make_float4(y0.x, y0.y, y1.x, y1.y);
            *reinterpret_cast<float4*>(&b2[r*SB + c0 + 2]) = make_float4(y2.x, y2.y, y3.x, y3.y);
        }

        // S3: W[i][p] = sum_m Y[i][m]*conj(F[m][p]) ; * twinv ; -> b1 (own rows)
        {
            f32x2 A0={0,0}, A1={0,0}, A2={0,0}, A3={0,0};
            #pragma unroll 16
            for (int m = 0; m < 32; ++m) {
                f32x2 yv = b2[r*SB + m];
                uint4 g4 = *reinterpret_cast<const uint4*>(&cFp[m*ST + c0]);
                vcmacC(A0, yv, upk(g4.x));
                vcmacC(A1, yv, upk(g4.y));
                vcmacC(A2, yv, upk(g4.z));
                vcmacC(A3, yv, upk(g4.w));
            }
            uint4 w4 = *reinterpret_cast<const uint4*>(&cTwip[r*ST + c0]);
            f32x2 z0 = vcmul(A0, upk(w4.x));
            f32x2 z1 = vcmul(A1, upk(w4.y));
            f32x2 z2 = vcmul(A2, upk(w4.z));
            f32x2 z3 = vcmul(A3, upk(w4.w));
            *reinterpret_cast<float4*>(&b1[r*SB + c0    ]) = make_float4(z0.x, z0.y, z1.x, z1.y);
            *reinterpret_cast<float4*>(&b1[r*SB + c0 + 2]) = make_float4(z2.x, z2.y, z3.x, z3.y);
        }

        __syncthreads();   // barrier B: all Z rows ready; aAp[cur] reads done

        // stage next pair into the other buffer
        if (ii < PASSES - 1) {
            uint4 av;
            av.x = pk2(pe.x, po.x); av.y = pk2(pe.y, po.y);
            av.z = pk2(pe.z, po.z); av.w = pk2(pe.w, po.w);
            *reinterpret_cast<uint4*>(&aAp[cur ^ 1][r*ST + c0]) = av;
        }

        // S4: O[q][p] = sum_i conj(F[q][i])*Z[i][p] ; Re -> tile 2p, Im -> tile 2p+1
        {
            f32x2 O0={0,0}, O1={0,0}, O2={0,0}, O3={0,0};
            #pragma unroll 16
            for (int i = 0; i < 32; ++i) {
                f32x2 gv = upk(cFp[r*ST + i]);
                float4 p01 = *reinterpret_cast<const float4*>(&b1[i*SB + c0]);
                float4 p23 = *reinterpret_cast<const float4*>(&b1[i*SB + c0 + 2]);
                vcmacC(O0, (f32x2){p01.x, p01.y}, gv);
                vcmacC(O1, (f32x2){p01.z, p01.w}, gv);
                vcmacC(O2, (f32x2){p23.x, p23.y}, gv);
                vcmacC(O3, (f32x2){p23.z, p23.w}, gv);
            }
            *reinterpret_cast<float4*>(OUT + be + 4*t) =
                make_float4(O0.x, O1.x, O2.x, O3.x);
            *reinterpret_cast<float4*>(OUT + be + 1048576 + 4*t) =
                make_float4(O0.y, O1.y, O2.y, O3.y);
        }
    }
}

extern "C" void kernel_launch(void* const* d_in, const int* in_sizes, int n_in,
                              void* d_out, int out_size, void* d_ws, size_t ws_size,
                              hipStream_t stream) {
    const float* U = (const float*)d_in[0];
    const float* K = (const float*)d_in[1];
    float* OUT = (float*)d_out;

    if (ws_size >= (size_t)4 * 1024 * 1024) {
        unsigned int* kf = (unsigned int*)d_ws;
        kfft_pre6<<<dim3(1024), dim3(256), 0, stream>>>(K, kf);
        tkmon6<2, true><<<dim3(4096), dim3(256), 0, stream>>>(U, K, kf, OUT);
    } else {
        tkmon6<4, false><<<dim3(2048), dim3(256), 0, stream>>>(U, K, nullptr, OUT);
    }
}

// Round 17
// 141.510 us; speedup vs baseline: 2.3509x; 1.1488x over previous
//
#include <hip/hip_runtime.h>
#include <hip/hip_bf16.h>

typedef float f32x2 __attribute__((ext_vector_type(2)));

#define ST 36                      // u32 stride for packed tables (144 B rows)
#define SF2 34                     // float2 stride for f32 tables/buffers (272 B rows)
#define KIDX(i) ((i) + ((i) >> 5)) // +1-per-32 padded f32 k-row addressing
#define W32A 0.19634954084936207f  // 2*pi/32
#define W1KA 0.006135923151542565f // 2*pi/1024
#define SC1K 0.0009765625f         // 2^-10 (exact)

__device__ __forceinline__ unsigned short f2bf(float x) {
    union { __hip_bfloat16 h; unsigned short u; } cv;
    cv.h = __float2bfloat16(x);
    return cv.u;
}
__device__ __forceinline__ float bfb2f(unsigned short b) {
    union { unsigned int u; float f; } cv;
    cv.u = ((unsigned int)b) << 16;
    return cv.f;
}
__device__ __forceinline__ float rt_bf(float x) { return bfb2f(f2bf(x)); }
__device__ __forceinline__ unsigned int pk2(float re, float im) {
    return (unsigned int)f2bf(re) | ((unsigned int)f2bf(im) << 16);
}
__device__ __forceinline__ f32x2 upk(unsigned int p) {
    union { unsigned int u; float f; } a, b;
    a.u = p << 16;
    b.u = p & 0xFFFF0000u;
    return (f32x2){a.f, b.f};
}
// complex a += x*y   (2 × v_pk_fma_f32)
__device__ __forceinline__ void vcmac(f32x2& a, f32x2 x, f32x2 y) {
    a = __builtin_elementwise_fma((f32x2){x.x, x.x}, y, a);
    a = __builtin_elementwise_fma((f32x2){-x.y, x.y}, (f32x2){y.y, y.x}, a);
}
// complex a += x*conj(y)
__device__ __forceinline__ void vcmacC(f32x2& a, f32x2 x, f32x2 y) {
    a = __builtin_elementwise_fma((f32x2){y.x, y.x}, x, a);
    a = __builtin_elementwise_fma((f32x2){x.y, -x.x}, (f32x2){y.y, y.y}, a);
}
__device__ __forceinline__ f32x2 vcmul(f32x2 x, f32x2 y) {
    f32x2 r = (f32x2){0.f, 0.f};
    vcmac(r, x, y);
    return r;
}
__device__ __forceinline__ float2 cmul2(float2 a, float2 b) {
    return make_float2(a.x*b.x - a.y*b.y, a.x*b.y + a.y*b.x);
}

// ---------- standalone per-h k-FFT: KF[h*1024+i*32+j]=pack(k_hat[i+32j]) ----------
__global__ __launch_bounds__(256) void kfft_pre7(const float* __restrict__ K,
                                                 unsigned int* __restrict__ KF)
{
    __shared__ float sk[1056];
    __shared__ float2 cT[32*SF2];
    const int t = threadIdx.x, h = blockIdx.x;
    #pragma unroll
    for (int s = 0; s < 4; ++s) {
        int i = t + 256*s;
        sk[KIDX(i)] = K[(size_t)h*1024 + i];
    }
    __syncthreads();
    const int i0 = t >> 3, q0 = (t & 7) << 2;
    float si, ci;
    sincosf(W32A * (float)i0, &si, &ci);
    const float2 stepi = make_float2(ci, -si);
    #pragma unroll
    for (int cc = q0; cc < q0 + 4; ++cc) {
        float2 wv = make_float2(1.f, 0.f), acc = make_float2(0.f, 0.f);
        for (int rr = 0; rr < 32; ++rr) {
            float kv = sk[KIDX(32*rr + cc)];
            acc.x = fmaf(kv, wv.x, acc.x);
            acc.y = fmaf(kv, wv.y, acc.y);
            wv = cmul2(wv, stepi);
        }
        float sp, cp;
        sincosf(W1KA * (float)(i0 * cc), &sp, &cp);
        cT[i0*SF2 + cc] = cmul2(acc, make_float2(cp, -sp));
    }
    __syncthreads();
    #pragma unroll
    for (int j = q0; j < q0 + 4; ++j) {
        float sj, cj;
        sincosf(W32A * (float)j, &sj, &cj);
        const float2 stepj = make_float2(cj, -sj);
        float2 wv = make_float2(1.f, 0.f), acc = make_float2(0.f, 0.f);
        for (int cc = 0; cc < 32; ++cc) {
            float2 tv = cT[i0*SF2 + cc];
            acc.x = fmaf(tv.x, wv.x, fmaf(-tv.y, wv.y, acc.x));
            acc.y = fmaf(tv.x, wv.y, fmaf( tv.y, wv.x, acc.y));
            wv = cmul2(wv, stepj);
        }
        KF[(size_t)h*1024 + i0*32 + j] = pk2(acc.x, acc.y);
    }
}

// ---------- main fused monarch conv; PASSES pairs per block ----------
template<int PASSES, bool USEKF>
__global__ __launch_bounds__(256) void tkmon7(
    const float* __restrict__ U, const float* __restrict__ K,
    const unsigned int* __restrict__ KF, float* __restrict__ OUT)
{
    constexpr int SH = (PASSES == 2) ? 2 : 1;
    __shared__ float2 cF2[32*SF2];          // F as f32 (bf16-rounded values); Finv = conj
    __shared__ unsigned int cTwip[32*ST];   // packed twinv ; tw = conj(twinv)*2^-10
    __shared__ unsigned int cKfp[32*ST];    // packed kfT
    __shared__ float2 aA2[2][32*SF2];       // double-buffered complex u pair, f32
    __shared__ f32x2 b1[32*SF2];            // stage buffer (X1tw, then Z); CT scratch
    __shared__ f32x2 b2[32*SF2];            // stage buffer (Y); hosts sk pre-loop

    const int t  = threadIdx.x;
    const int h  = blockIdx.x >> SH;
    const int p0 = (blockIdx.x & ((1 << SH) - 1)) * PASSES;
    const int r  = t >> 3;
    const int c0 = (t & 7) << 2;

    // ---- generate twiddle tables (F as f32 bf16-rounded; twinv packed) ----
    #pragma unroll
    for (int ii = 0; ii < 4; ++ii) {
        int idx = 4*t + ii;
        int rr = idx >> 5, cc = idx & 31;
        int m32 = (rr * cc) & 31;
        float s32, c32; sincosf((float)m32 * W32A, &s32, &c32);
        cF2[rr*SF2 + cc] = make_float2(rt_bf(c32), rt_bf(-s32));
        int m1k = (rr * cc) & 1023;
        float s1k, c1k; sincosf((float)m1k * W1KA, &s1k, &c1k);
        cTwip[rr*ST + cc] = pk2(c1k, s1k);
    }

    if (USEKF) {
        uint4 kv = *reinterpret_cast<const uint4*>(&KF[(size_t)h*1024 + 4*t]);
        *reinterpret_cast<uint4*>(&cKfp[r*ST + c0]) = kv;
    } else {
        float* sk = reinterpret_cast<float*>(b2);
        #pragma unroll
        for (int s = 0; s < 4; ++s) {
            int i = t + 256*s;
            sk[KIDX(i)] = K[(size_t)h*1024 + i];
        }
        __syncthreads();
        float2* cT = reinterpret_cast<float2*>(b1);
        const int i0 = t >> 3, q0 = (t & 7) << 2;
        float si, ci;
        sincosf(W32A * (float)i0, &si, &ci);
        const float2 stepi = make_float2(ci, -si);
        #pragma unroll
        for (int cc = q0; cc < q0 + 4; ++cc) {
            float2 wv = make_float2(1.f, 0.f), acc = make_float2(0.f, 0.f);
            for (int rr = 0; rr < 32; ++rr) {
                float kv = sk[KIDX(32*rr + cc)];
                acc.x = fmaf(kv, wv.x, acc.x);
                acc.y = fmaf(kv, wv.y, acc.y);
                wv = cmul2(wv, stepi);
            }
            float sp, cp;
            sincosf(W1KA * (float)(i0 * cc), &sp, &cp);
            cT[i0*SF2 + cc] = cmul2(acc, make_float2(cp, -sp));
        }
        __syncthreads();
        #pragma unroll
        for (int j = q0; j < q0 + 4; ++j) {
            float sj, cj;
            sincosf(W32A * (float)j, &sj, &cj);
            const float2 stepj = make_float2(cj, -sj);
            float2 wv = make_float2(1.f, 0.f), acc = make_float2(0.f, 0.f);
            for (int cc = 0; cc < 32; ++cc) {
                float2 tv = cT[i0*SF2 + cc];
                acc.x = fmaf(tv.x, wv.x, fmaf(-tv.y, wv.y, acc.x));
                acc.y = fmaf(tv.x, wv.y, fmaf( tv.y, wv.x, acc.y));
                wv = cmul2(wv, stepj);
            }
            cKfp[i0*ST + j] = pk2(acc.x, acc.y);
        }
    }

    // ---- prologue: stage first pass pair into aA2[0] (f32 complex) ----
    {
        const size_t be = ((size_t)(2*p0) * 1024 + h) * 1024;
        float4 ue = *reinterpret_cast<const float4*>(U + be + 4*t);
        float4 uo = *reinterpret_cast<const float4*>(U + be + 1048576 + 4*t);
        *reinterpret_cast<float4*>(&aA2[0][r*SF2 + c0]) =
            make_float4(rt_bf(ue.x), rt_bf(uo.x), rt_bf(ue.y), rt_bf(uo.y));
        *reinterpret_cast<float4*>(&aA2[0][r*SF2 + c0 + 2]) =
            make_float4(rt_bf(ue.z), rt_bf(uo.z), rt_bf(ue.w), rt_bf(uo.w));
    }

    const f32x2 scv = {SC1K, -SC1K};

    // ==== PASSES passes (2 b-tiles each), 2 barriers per pass ====
    for (int ii = 0; ii < PASSES; ++ii) {
        const int pass = p0 + ii;
        const int cur  = ii & 1;
        const size_t be = ((size_t)(2*pass) * 1024 + h) * 1024;

        __syncthreads();   // barrier A: aA2[cur] + tables/kf visible; b1 free

        // S1: X1[i][c] = sum_j F[i][j]*Z[j][c] ; * tw ; -> b1
        {
            f32x2 A0={0,0}, A1={0,0}, A2={0,0}, A3={0,0};
            #pragma unroll 16
            for (int j = 0; j < 32; ++j) {
                float2 fv2 = cF2[r*SF2 + j];
                f32x2 fv = {fv2.x, fv2.y};
                float4 a01 = *reinterpret_cast<const float4*>(&aA2[cur][j*SF2 + c0]);
                float4 a23 = *reinterpret_cast<const float4*>(&aA2[cur][j*SF2 + c0 + 2]);
                vcmac(A0, fv, (f32x2){a01.x, a01.y});
                vcmac(A1, fv, (f32x2){a01.z, a01.w});
                vcmac(A2, fv, (f32x2){a23.x, a23.y});
                vcmac(A3, fv, (f32x2){a23.z, a23.w});
            }
            uint4 w4 = *reinterpret_cast<const uint4*>(&cTwip[r*ST + c0]);
            f32x2 x0 = vcmul(A0, upk(w4.x) * scv);
            f32x2 x1 = vcmul(A1, upk(w4.y) * scv);
            f32x2 x2 = vcmul(A2, upk(w4.z) * scv);
            f32x2 x3 = vcmul(A3, upk(w4.w) * scv);
            *reinterpret_cast<float4*>(&b1[r*SF2 + c0    ]) = make_float4(x0.x, x0.y, x1.x, x1.y);
            *reinterpret_cast<float4*>(&b1[r*SF2 + c0 + 2]) = make_float4(x2.x, x2.y, x3.x, x3.y);
        }

        // prefetch next pass's pair (latency hidden under S2+S3)
        float4 pe, po;
        if (ii < PASSES - 1) {
            const size_t nb = ((size_t)(2*pass + 2) * 1024 + h) * 1024;
            pe = *reinterpret_cast<const float4*>(U + nb + 4*t);
            po = *reinterpret_cast<const float4*>(U + nb + 1048576 + 4*t);
        }

        // S2: X2[i][m] = sum_c X1tw[i][c]*F[c][m] ; * kf ; -> b2 (own rows)
        {
            f32x2 A0={0,0}, A1={0,0}, A2={0,0}, A3={0,0};
            #pragma unroll 16
            for (int c = 0; c < 32; ++c) {
                f32x2 xv = b1[r*SF2 + c];
                float4 f01 = *reinterpret_cast<const float4*>(&cF2[c*SF2 + c0]);
                float4 f23 = *reinterpret_cast<const float4*>(&cF2[c*SF2 + c0 + 2]);
                vcmac(A0, xv, (f32x2){f01.x, f01.y});
                vcmac(A1, xv, (f32x2){f01.z, f01.w});
                vcmac(A2, xv, (f32x2){f23.x, f23.y});
                vcmac(A3, xv, (f32x2){f23.z, f23.w});
            }
            uint4 k4 = *reinterpret_cast<const uint4*>(&cKfp[r*ST + c0]);
            f32x2 y0 = vcmul(A0, upk(k4.x));
            f32x2 y1 = vcmul(A1, upk(k4.y));
            f32x2 y2 = vcmul(A2, upk(k4.z));
            f32x2 y3 = vcmul(A3, upk(k4.w));
            *reinterpret_cast<float4*>(&b2[r*SF2 + c0    ]) = make_float4(y0.x, y0.y, y1.x, y1.y);
            *reinterpret_cast<float4*>(&b2[r*SF2 + c0 + 2]) = make_float4(y2.x, y2.y, y3.x, y3.y);
        }

        // S3: W[i][p] = sum_m Y[i][m]*conj(F[m][p]) ; * twinv ; -> b1 (own rows)
        {
            f32x2 A0={0,0}, A1={0,0}, A2={0,0}, A3={0,0};
            #pragma unroll 16
            for (int m = 0; m < 32; ++m) {
                f32x2 yv = b2[r*SF2 + m];
                float4 g01 = *reinterpret_cast<const float4*>(&cF2[m*SF2 + c0]);
                float4 g23 = *reinterpret_cast<const float4*>(&cF2[m*SF2 + c0 + 2]);
                vcmacC(A0, yv, (f32x2){g01.x, g01.y});
                vcmacC(A1, yv, (f32x2){g01.z, g01.w});
                vcmacC(A2, yv, (f32x2){g23.x, g23.y});
                vcmacC(A3, yv, (f32x2){g23.z, g23.w});
            }
            uint4 w4 = *reinterpret_cast<const uint4*>(&cTwip[r*ST + c0]);
            f32x2 z0 = vcmul(A0, upk(w4.x));
            f32x2 z1 = vcmul(A1, upk(w4.y));
            f32x2 z2 = vcmul(A2, upk(w4.z));
            f32x2 z3 = vcmul(A3, upk(w4.w));
            *reinterpret_cast<float4*>(&b1[r*SF2 + c0    ]) = make_float4(z0.x, z0.y, z1.x, z1.y);
            *reinterpret_cast<float4*>(&b1[r*SF2 + c0 + 2]) = make_float4(z2.x, z2.y, z3.x, z3.y);
        }

        __syncthreads();   // barrier B: all Z rows ready; aA2[cur] reads done

        // stage next pair into the other buffer
        if (ii < PASSES - 1) {
            *reinterpret_cast<float4*>(&aA2[cur ^ 1][r*SF2 + c0]) =
                make_float4(rt_bf(pe.x), rt_bf(po.x), rt_bf(pe.y), rt_bf(po.y));
            *reinterpret_cast<float4*>(&aA2[cur ^ 1][r*SF2 + c0 + 2]) =
                make_float4(rt_bf(pe.z), rt_bf(po.z), rt_bf(pe.w), rt_bf(po.w));
        }

        // S4: O[q][p] = sum_i conj(F[q][i])*Z[i][p] ; Re -> tile 2p, Im -> tile 2p+1
        {
            f32x2 O0={0,0}, O1={0,0}, O2={0,0}, O3={0,0};
            #pragma unroll 16
            for (int i = 0; i < 32; ++i) {
                float2 gv2 = cF2[r*SF2 + i];
                f32x2 gv = {gv2.x, gv2.y};
                float4 p01 = *reinterpret_cast<const float4*>(&b1[i*SF2 + c0]);
                float4 p23 = *reinterpret_cast<const float4*>(&b1[i*SF2 + c0 + 2]);
                vcmacC(O0, (f32x2){p01.x, p01.y}, gv);
                vcmacC(O1, (f32x2){p01.z, p01.w}, gv);
                vcmacC(O2, (f32x2){p23.x, p23.y}, gv);
                vcmacC(O3, (f32x2){p23.z, p23.w}, gv);
            }
            *reinterpret_cast<float4*>(OUT + be + 4*t) =
                make_float4(O0.x, O1.x, O2.x, O3.x);
            *reinterpret_cast<float4*>(OUT + be + 1048576 + 4*t) =
                make_float4(O0.y, O1.y, O2.y, O3.y);
        }
    }
}

extern "C" void kernel_launch(void* const* d_in, const int* in_sizes, int n_in,
                              void* d_out, int out_size, void* d_ws, size_t ws_size,
                              hipStream_t stream) {
    const float* U = (const float*)d_in[0];
    const float* K = (const float*)d_in[1];
    float* OUT = (float*)d_out;

    if (ws_size >= (size_t)4 * 1024 * 1024) {
        unsigned int* kf = (unsigned int*)d_ws;
        kfft_pre7<<<dim3(1024), dim3(256), 0, stream>>>(K, kf);
        tkmon7<2, true><<<dim3(4096), dim3(256), 0, stream>>>(U, K, kf, OUT);
    } else {
        tkmon7<4, false><<<dim3(2048), dim3(256), 0, stream>>>(U, K, nullptr, OUT);
    }
}

// Round 18
// 135.072 us; speedup vs baseline: 2.4630x; 1.0477x over previous
//
#include <hip/hip_runtime.h>
#include <hip/hip_bf16.h>

typedef float f32x2 __attribute__((ext_vector_type(2)));

#define ST 36                      // u32 stride for packed tables (144 B rows)
#define SF2 34                     // float2 stride for f32 tables/buffers (272 B rows)
#define KIDX(i) ((i) + ((i) >> 5)) // +1-per-32 padded f32 k-row addressing
#define W32A 0.19634954084936207f  // 2*pi/32
#define W1KA 0.006135923151542565f // 2*pi/1024
#define SC1K 0.0009765625f         // 2^-10 (exact)

__device__ __forceinline__ unsigned short f2bf(float x) {
    union { __hip_bfloat16 h; unsigned short u; } cv;
    cv.h = __float2bfloat16(x);
    return cv.u;
}
__device__ __forceinline__ float bfb2f(unsigned short b) {
    union { unsigned int u; float f; } cv;
    cv.u = ((unsigned int)b) << 16;
    return cv.f;
}
__device__ __forceinline__ float rt_bf(float x) { return bfb2f(f2bf(x)); }
__device__ __forceinline__ unsigned int pk2(float re, float im) {
    return (unsigned int)f2bf(re) | ((unsigned int)f2bf(im) << 16);
}
__device__ __forceinline__ f32x2 upk(unsigned int p) {
    union { unsigned int u; float f; } a, b;
    a.u = p << 16;
    b.u = p & 0xFFFF0000u;
    return (f32x2){a.f, b.f};
}
// complex a += x*y   (2 × v_pk_fma_f32)
__device__ __forceinline__ void vcmac(f32x2& a, f32x2 x, f32x2 y) {
    a = __builtin_elementwise_fma((f32x2){x.x, x.x}, y, a);
    a = __builtin_elementwise_fma((f32x2){-x.y, x.y}, (f32x2){y.y, y.x}, a);
}
// complex a += x*conj(y)
__device__ __forceinline__ void vcmacC(f32x2& a, f32x2 x, f32x2 y) {
    a = __builtin_elementwise_fma((f32x2){y.x, y.x}, x, a);
    a = __builtin_elementwise_fma((f32x2){x.y, -x.x}, (f32x2){y.y, y.y}, a);
}
__device__ __forceinline__ f32x2 vcmul(f32x2 x, f32x2 y) {
    f32x2 r = (f32x2){0.f, 0.f};
    vcmac(r, x, y);
    return r;
}
__device__ __forceinline__ float2 cmul2(float2 a, float2 b) {
    return make_float2(a.x*b.x - a.y*b.y, a.x*b.y + a.y*b.x);
}

// ---------- standalone per-h k-FFT: KF[h*1024+i*32+j]=pack(k_hat[i+32j]) ----------
__global__ __launch_bounds__(256) void kfft_pre8(const float* __restrict__ K,
                                                 unsigned int* __restrict__ KF)
{
    __shared__ float sk[1056];
    __shared__ float2 cT[32*SF2];
    const int t = threadIdx.x, h = blockIdx.x;
    #pragma unroll
    for (int s = 0; s < 4; ++s) {
        int i = t + 256*s;
        sk[KIDX(i)] = K[(size_t)h*1024 + i];
    }
    __syncthreads();
    const int i0 = t >> 3, q0 = (t & 7) << 2;
    float si, ci;
    sincosf(W32A * (float)i0, &si, &ci);
    const float2 stepi = make_float2(ci, -si);
    #pragma unroll
    for (int cc = q0; cc < q0 + 4; ++cc) {
        float2 wv = make_float2(1.f, 0.f), acc = make_float2(0.f, 0.f);
        for (int rr = 0; rr < 32; ++rr) {
            float kv = sk[KIDX(32*rr + cc)];
            acc.x = fmaf(kv, wv.x, acc.x);
            acc.y = fmaf(kv, wv.y, acc.y);
            wv = cmul2(wv, stepi);
        }
        float sp, cp;
        sincosf(W1KA * (float)(i0 * cc), &sp, &cp);
        cT[i0*SF2 + cc] = cmul2(acc, make_float2(cp, -sp));
    }
    __syncthreads();
    #pragma unroll
    for (int j = q0; j < q0 + 4; ++j) {
        float sj, cj;
        sincosf(W32A * (float)j, &sj, &cj);
        const float2 stepj = make_float2(cj, -sj);
        float2 wv = make_float2(1.f, 0.f), acc = make_float2(0.f, 0.f);
        for (int cc = 0; cc < 32; ++cc) {
            float2 tv = cT[i0*SF2 + cc];
            acc.x = fmaf(tv.x, wv.x, fmaf(-tv.y, wv.y, acc.x));
            acc.y = fmaf(tv.x, wv.y, fmaf( tv.y, wv.x, acc.y));
            wv = cmul2(wv, stepj);
        }
        KF[(size_t)h*1024 + i0*32 + j] = pk2(acc.x, acc.y);
    }
}

// ---------- main fused monarch conv; PASSES pairs per block ----------
template<int PASSES, bool USEKF>
__global__ __launch_bounds__(256) void tkmon8(
    const float* __restrict__ U, const float* __restrict__ K,
    const unsigned int* __restrict__ KF, float* __restrict__ OUT)
{
    constexpr int SH = (PASSES == 2) ? 2 : 1;
    __shared__ float2 cF2[32*SF2];          // F as f32 (bf16-rounded); Finv = conj
    __shared__ unsigned int cTwip[32*ST];   // packed twinv ; tw = conj(twinv)*2^-10
    __shared__ unsigned int cKfp[32*ST];    // packed kfT
    __shared__ float2 aA2[32*SF2];          // single-buffered complex u pair (f32)
    __shared__ f32x2 b1[32*SF2];            // in-place stage buffer; CT scratch

    const int t  = threadIdx.x;
    const int h  = blockIdx.x >> SH;
    const int p0 = (blockIdx.x & ((1 << SH) - 1)) * PASSES;
    const int r  = t >> 3;
    const int c0 = (t & 7) << 2;

    // ---- generate twiddle tables (F as f32 bf16-rounded; twinv packed) ----
    #pragma unroll
    for (int ii = 0; ii < 4; ++ii) {
        int idx = 4*t + ii;
        int rr = idx >> 5, cc = idx & 31;
        int m32 = (rr * cc) & 31;
        float s32, c32; sincosf((float)m32 * W32A, &s32, &c32);
        cF2[rr*SF2 + cc] = make_float2(rt_bf(c32), rt_bf(-s32));
        int m1k = (rr * cc) & 1023;
        float s1k, c1k; sincosf((float)m1k * W1KA, &s1k, &c1k);
        cTwip[rr*ST + cc] = pk2(c1k, s1k);
    }

    if (USEKF) {
        uint4 kv = *reinterpret_cast<const uint4*>(&KF[(size_t)h*1024 + 4*t]);
        *reinterpret_cast<uint4*>(&cKfp[r*ST + c0]) = kv;
    } else {
        // in-block k-FFT; sk overlays aA2 (dead until prologue), cT in b1
        float* sk = reinterpret_cast<float*>(aA2);
        #pragma unroll
        for (int s = 0; s < 4; ++s) {
            int i = t + 256*s;
            sk[KIDX(i)] = K[(size_t)h*1024 + i];
        }
        __syncthreads();
        float2* cT = reinterpret_cast<float2*>(b1);
        const int i0 = t >> 3, q0 = (t & 7) << 2;
        float si, ci;
        sincosf(W32A * (float)i0, &si, &ci);
        const float2 stepi = make_float2(ci, -si);
        #pragma unroll
        for (int cc = q0; cc < q0 + 4; ++cc) {
            float2 wv = make_float2(1.f, 0.f), acc = make_float2(0.f, 0.f);
            for (int rr = 0; rr < 32; ++rr) {
                float kv = sk[KIDX(32*rr + cc)];
                acc.x = fmaf(kv, wv.x, acc.x);
                acc.y = fmaf(kv, wv.y, acc.y);
                wv = cmul2(wv, stepi);
            }
            float sp, cp;
            sincosf(W1KA * (float)(i0 * cc), &sp, &cp);
            cT[i0*SF2 + cc] = cmul2(acc, make_float2(cp, -sp));
        }
        __syncthreads();   // all sk reads done; aA2 reusable after this point
        #pragma unroll
        for (int j = q0; j < q0 + 4; ++j) {
            float sj, cj;
            sincosf(W32A * (float)j, &sj, &cj);
            const float2 stepj = make_float2(cj, -sj);
            float2 wv = make_float2(1.f, 0.f), acc = make_float2(0.f, 0.f);
            for (int cc = 0; cc < 32; ++cc) {
                float2 tv = cT[i0*SF2 + cc];
                acc.x = fmaf(tv.x, wv.x, fmaf(-tv.y, wv.y, acc.x));
                acc.y = fmaf(tv.x, wv.y, fmaf( tv.y, wv.x, acc.y));
                wv = cmul2(wv, stepj);
            }
            cKfp[i0*ST + j] = pk2(acc.x, acc.y);
        }
    }

    // ---- prologue: stage first pass pair into aA2 (f32 complex) ----
    {
        const size_t be = ((size_t)(2*p0) * 1024 + h) * 1024;
        float4 ue = *reinterpret_cast<const float4*>(U + be + 4*t);
        float4 uo = *reinterpret_cast<const float4*>(U + be + 1048576 + 4*t);
        *reinterpret_cast<float4*>(&aA2[r*SF2 + c0]) =
            make_float4(rt_bf(ue.x), rt_bf(uo.x), rt_bf(ue.y), rt_bf(uo.y));
        *reinterpret_cast<float4*>(&aA2[r*SF2 + c0 + 2]) =
            make_float4(rt_bf(ue.z), rt_bf(uo.z), rt_bf(ue.w), rt_bf(uo.w));
    }

    const f32x2 scv = {SC1K, -SC1K};

    // ==== PASSES passes (2 b-tiles each), 2 barriers per pass ====
    for (int ii = 0; ii < PASSES; ++ii) {
        const int pass = p0 + ii;
        const size_t be = ((size_t)(2*pass) * 1024 + h) * 1024;

        __syncthreads();   // barrier A: aA2 + tables/kf visible; b1 free

        // S1: X1[i][c] = sum_j F[i][j]*Z[j][c] ; * tw ; -> b1 (own rows)
        {
            f32x2 A0={0,0}, A1={0,0}, A2={0,0}, A3={0,0};
            #pragma unroll 16
            for (int j = 0; j < 32; ++j) {
                float2 fv2 = cF2[r*SF2 + j];
                f32x2 fv = {fv2.x, fv2.y};
                float4 a01 = *reinterpret_cast<const float4*>(&aA2[j*SF2 + c0]);
                float4 a23 = *reinterpret_cast<const float4*>(&aA2[j*SF2 + c0 + 2]);
                vcmac(A0, fv, (f32x2){a01.x, a01.y});
                vcmac(A1, fv, (f32x2){a01.z, a01.w});
                vcmac(A2, fv, (f32x2){a23.x, a23.y});
                vcmac(A3, fv, (f32x2){a23.z, a23.w});
            }
            uint4 w4 = *reinterpret_cast<const uint4*>(&cTwip[r*ST + c0]);
            f32x2 x0 = vcmul(A0, upk(w4.x) * scv);
            f32x2 x1 = vcmul(A1, upk(w4.y) * scv);
            f32x2 x2 = vcmul(A2, upk(w4.z) * scv);
            f32x2 x3 = vcmul(A3, upk(w4.w) * scv);
            *reinterpret_cast<float4*>(&b1[r*SF2 + c0    ]) = make_float4(x0.x, x0.y, x1.x, x1.y);
            *reinterpret_cast<float4*>(&b1[r*SF2 + c0 + 2]) = make_float4(x2.x, x2.y, x3.x, x3.y);
        }

        // prefetch next pass's pair (latency hidden under S2+S3)
        float4 pe, po;
        if (ii < PASSES - 1) {
            const size_t nb = ((size_t)(2*pass + 2) * 1024 + h) * 1024;
            pe = *reinterpret_cast<const float4*>(U + nb + 4*t);
            po = *reinterpret_cast<const float4*>(U + nb + 1048576 + 4*t);
        }

        // S2: X2[i][m] = sum_c X1tw[i][c]*F[c][m] ; * kf ; in-place b1 (own rows:
        //     all reads of row r issue before this wave's writes; rows wave-private)
        {
            f32x2 A0={0,0}, A1={0,0}, A2={0,0}, A3={0,0};
            #pragma unroll 16
            for (int c = 0; c < 32; ++c) {
                f32x2 xv = b1[r*SF2 + c];
                float4 f01 = *reinterpret_cast<const float4*>(&cF2[c*SF2 + c0]);
                float4 f23 = *reinterpret_cast<const float4*>(&cF2[c*SF2 + c0 + 2]);
                vcmac(A0, xv, (f32x2){f01.x, f01.y});
                vcmac(A1, xv, (f32x2){f01.z, f01.w});
                vcmac(A2, xv, (f32x2){f23.x, f23.y});
                vcmac(A3, xv, (f32x2){f23.z, f23.w});
            }
            uint4 k4 = *reinterpret_cast<const uint4*>(&cKfp[r*ST + c0]);
            f32x2 y0 = vcmul(A0, upk(k4.x));
            f32x2 y1 = vcmul(A1, upk(k4.y));
            f32x2 y2 = vcmul(A2, upk(k4.z));
            f32x2 y3 = vcmul(A3, upk(k4.w));
            *reinterpret_cast<float4*>(&b1[r*SF2 + c0    ]) = make_float4(y0.x, y0.y, y1.x, y1.y);
            *reinterpret_cast<float4*>(&b1[r*SF2 + c0 + 2]) = make_float4(y2.x, y2.y, y3.x, y3.y);
        }

        // S3: W[i][p] = sum_m Y[i][m]*conj(F[m][p]) ; * twinv ; in-place b1 (own rows)
        {
            f32x2 A0={0,0}, A1={0,0}, A2={0,0}, A3={0,0};
            #pragma unroll 16
            for (int m = 0; m < 32; ++m) {
                f32x2 yv = b1[r*SF2 + m];
                float4 g01 = *reinterpret_cast<const float4*>(&cF2[m*SF2 + c0]);
                float4 g23 = *reinterpret_cast<const float4*>(&cF2[m*SF2 + c0 + 2]);
                vcmacC(A0, yv, (f32x2){g01.x, g01.y});
                vcmacC(A1, yv, (f32x2){g01.z, g01.w});
                vcmacC(A2, yv, (f32x2){g23.x, g23.y});
                vcmacC(A3, yv, (f32x2){g23.z, g23.w});
            }
            uint4 w4 = *reinterpret_cast<const uint4*>(&cTwip[r*ST + c0]);
            f32x2 z0 = vcmul(A0, upk(w4.x));
            f32x2 z1 = vcmul(A1, upk(w4.y));
            f32x2 z2 = vcmul(A2, upk(w4.z));
            f32x2 z3 = vcmul(A3, upk(w4.w));
            *reinterpret_cast<float4*>(&b1[r*SF2 + c0    ]) = make_float4(z0.x, z0.y, z1.x, z1.y);
            *reinterpret_cast<float4*>(&b1[r*SF2 + c0 + 2]) = make_float4(z2.x, z2.y, z3.x, z3.y);
        }

        __syncthreads();   // barrier B: all Z rows ready; aA2 reads done

        // stage next pair (aA2 dead until next pass's S1, which is after barrier A)
        if (ii < PASSES - 1) {
            *reinterpret_cast<float4*>(&aA2[r*SF2 + c0]) =
                make_float4(rt_bf(pe.x), rt_bf(po.x), rt_bf(pe.y), rt_bf(po.y));
            *reinterpret_cast<float4*>(&aA2[r*SF2 + c0 + 2]) =
                make_float4(rt_bf(pe.z), rt_bf(po.z), rt_bf(pe.w), rt_bf(po.w));
        }

        // S4: O[q][p] = sum_i conj(F[q][i])*Z[i][p] ; Re -> tile 2p, Im -> tile 2p+1
        {
            f32x2 O0={0,0}, O1={0,0}, O2={0,0}, O3={0,0};
            #pragma unroll 16
            for (int i = 0; i < 32; ++i) {
                float2 gv2 = cF2[r*SF2 + i];
                f32x2 gv = {gv2.x, gv2.y};
                float4 p01 = *reinterpret_cast<const float4*>(&b1[i*SF2 + c0]);
                float4 p23 = *reinterpret_cast<const float4*>(&b1[i*SF2 + c0 + 2]);
                vcmacC(O0, (f32x2){p01.x, p01.y}, gv);
                vcmacC(O1, (f32x2){p01.z, p01.w}, gv);
                vcmacC(O2, (f32x2){p23.x, p23.y}, gv);
                vcmacC(O3, (f32x2){p23.z, p23.w}, gv);
            }
            *reinterpret_cast<float4*>(OUT + be + 4*t) =
                make_float4(O0.x, O1.x, O2.x, O3.x);
            *reinterpret_cast<float4*>(OUT + be + 1048576 + 4*t) =
                make_float4(O0.y, O1.y, O2.y, O3.y);
        }
    }
}

extern "C" void kernel_launch(void* const* d_in, const int* in_sizes, int n_in,
                              void* d_out, int out_size, void* d_ws, size_t ws_size,
                              hipStream_t stream) {
    const float* U = (const float*)d_in[0];
    const float* K = (const float*)d_in[1];
    float* OUT = (float*)d_out;

    if (ws_size >= (size_t)4 * 1024 * 1024) {
        unsigned int* kf = (unsigned int*)d_ws;
        kfft_pre8<<<dim3(1024), dim3(256), 0, stream>>>(K, kf);
        tkmon8<2, true><<<dim3(4096), dim3(256), 0, stream>>>(U, K, kf, OUT);
    } else {
        tkmon8<4, false><<<dim3(2048), dim3(256), 0, stream>>>(U, K, nullptr, OUT);
    }
}

// Round 19
// 132.272 us; speedup vs baseline: 2.5151x; 1.0212x over previous
//
#include <hip/hip_runtime.h>
#include <hip/hip_bf16.h>

typedef float f32x2 __attribute__((ext_vector_type(2)));

#define SF2 34                     // float2 stride for f32 tables/buffers (272 B rows)
#define KIDX(i) ((i) + ((i) >> 5)) // +1-per-32 padded f32 k-row addressing
#define W32A 0.19634954084936207f  // 2*pi/32
#define W1KA 0.006135923151542565f // 2*pi/1024
#define SC1K 0.0009765625f         // 2^-10 (exact)

__device__ __forceinline__ unsigned short f2bf(float x) {
    union { __hip_bfloat16 h; unsigned short u; } cv;
    cv.h = __float2bfloat16(x);
    return cv.u;
}
__device__ __forceinline__ float bfb2f(unsigned short b) {
    union { unsigned int u; float f; } cv;
    cv.u = ((unsigned int)b) << 16;
    return cv.f;
}
__device__ __forceinline__ float rt_bf(float x) { return bfb2f(f2bf(x)); }
__device__ __forceinline__ unsigned int pk2(float re, float im) {
    return (unsigned int)f2bf(re) | ((unsigned int)f2bf(im) << 16);
}
__device__ __forceinline__ f32x2 upk(unsigned int p) {
    union { unsigned int u; float f; } a, b;
    a.u = p << 16;
    b.u = p & 0xFFFF0000u;
    return (f32x2){a.f, b.f};
}
// complex a += x*y (4 scalar v_fma after scalarization; neg via modifier)
__device__ __forceinline__ void vcmac(f32x2& a, f32x2 x, f32x2 y) {
    a = __builtin_elementwise_fma((f32x2){x.x, x.x}, y, a);
    a = __builtin_elementwise_fma((f32x2){-x.y, x.y}, (f32x2){y.y, y.x}, a);
}
// complex a += x*conj(y)
__device__ __forceinline__ void vcmacC(f32x2& a, f32x2 x, f32x2 y) {
    a = __builtin_elementwise_fma((f32x2){y.x, y.x}, x, a);
    a = __builtin_elementwise_fma((f32x2){x.y, -x.x}, (f32x2){y.y, y.y}, a);
}
__device__ __forceinline__ f32x2 vcmul(f32x2 x, f32x2 y) {
    f32x2 r = (f32x2){0.f, 0.f};
    vcmac(r, x, y);
    return r;
}
__device__ __forceinline__ float2 cmul2(float2 a, float2 b) {
    return make_float2(a.x*b.x - a.y*b.y, a.x*b.y + a.y*b.x);
}

// ---------- standalone per-h k-FFT: KF[h*1024+i*32+j]=pack(k_hat[i+32j]) ----------
__global__ __launch_bounds__(256) void kfft_pre9(const float* __restrict__ K,
                                                 unsigned int* __restrict__ KF)
{
    __shared__ float sk[1056];
    __shared__ float2 cT[32*SF2];
    const int t = threadIdx.x, h = blockIdx.x;
    #pragma unroll
    for (int s = 0; s < 4; ++s) {
        int i = t + 256*s;
        sk[KIDX(i)] = K[(size_t)h*1024 + i];
    }
    __syncthreads();
    const int i0 = t >> 3, q0 = (t & 7) << 2;
    float si, ci;
    sincosf(W32A * (float)i0, &si, &ci);
    const float2 stepi = make_float2(ci, -si);
    #pragma unroll
    for (int cc = q0; cc < q0 + 4; ++cc) {
        float2 wv = make_float2(1.f, 0.f), acc = make_float2(0.f, 0.f);
        for (int rr = 0; rr < 32; ++rr) {
            float kv = sk[KIDX(32*rr + cc)];
            acc.x = fmaf(kv, wv.x, acc.x);
            acc.y = fmaf(kv, wv.y, acc.y);
            wv = cmul2(wv, stepi);
        }
        float sp, cp;
        sincosf(W1KA * (float)(i0 * cc), &sp, &cp);
        cT[i0*SF2 + cc] = cmul2(acc, make_float2(cp, -sp));
    }
    __syncthreads();
    #pragma unroll
    for (int j = q0; j < q0 + 4; ++j) {
        float sj, cj;
        sincosf(W32A * (float)j, &sj, &cj);
        const float2 stepj = make_float2(cj, -sj);
        float2 wv = make_float2(1.f, 0.f), acc = make_float2(0.f, 0.f);
        for (int cc = 0; cc < 32; ++cc) {
            float2 tv = cT[i0*SF2 + cc];
            acc.x = fmaf(tv.x, wv.x, fmaf(-tv.y, wv.y, acc.x));
            acc.y = fmaf(tv.x, wv.y, fmaf( tv.y, wv.x, acc.y));
            wv = cmul2(wv, stepj);
        }
        KF[(size_t)h*1024 + i0*32 + j] = pk2(acc.x, acc.y);
    }
}

// ---------- main fused monarch conv; PASSES pairs per block ----------
template<int PASSES, bool USEKF>
__global__ __launch_bounds__(256) void tkmon9(
    const float* __restrict__ U, const float* __restrict__ K,
    const unsigned int* __restrict__ KF, float* __restrict__ OUT)
{
    constexpr int SH = (PASSES == 2) ? 2 : 1;
    __shared__ float2 cF2[32*SF2];   // F as f32 (bf16-rounded); Finv = conj
    __shared__ float2 aA2[32*SF2];   // complex u pair (f32); hosts sk in fallback
    __shared__ f32x2 b1[32*SF2];     // in-place stage buffer; CT scratch

    const int t  = threadIdx.x;
    const int h  = blockIdx.x >> SH;
    const int p0 = (blockIdx.x & ((1 << SH) - 1)) * PASSES;
    const int r  = t >> 3;
    const int c0 = (t & 7) << 2;

    // ---- F table (f32, bf16-rounded values) ----
    #pragma unroll
    for (int ii = 0; ii < 4; ++ii) {
        int idx = 4*t + ii;
        int rr = idx >> 5, cc = idx & 31;
        int m32 = (rr * cc) & 31;
        float s32, c32; sincosf((float)m32 * W32A, &s32, &c32);
        cF2[rr*SF2 + cc] = make_float2(rt_bf(c32), rt_bf(-s32));
    }

    // ---- thread-invariant epilogue factors in REGISTERS ----
    // twinv[r][c0+i] ; kf[r][c0+i]  (the only slots this thread ever uses)
    f32x2 twi[4], kfr[4];
    #pragma unroll
    for (int i = 0; i < 4; ++i) {
        int m1k = (r * (c0 + i)) & 1023;
        float s1k, c1k; sincosf((float)m1k * W1KA, &s1k, &c1k);
        twi[i] = (f32x2){rt_bf(c1k), rt_bf(s1k)};
    }

    if (USEKF) {
        // KF index of this thread's 4 slots: r*32+c0 == 4t  -> coalesced uint4
        uint4 kv = *reinterpret_cast<const uint4*>(&KF[(size_t)h*1024 + 4*t]);
        kfr[0] = upk(kv.x); kfr[1] = upk(kv.y);
        kfr[2] = upk(kv.z); kfr[3] = upk(kv.w);
    } else {
        // in-block k-FFT; sk overlays aA2 (dead until prologue), cT in b1
        float* sk = reinterpret_cast<float*>(aA2);
        #pragma unroll
        for (int s = 0; s < 4; ++s) {
            int i = t + 256*s;
            sk[KIDX(i)] = K[(size_t)h*1024 + i];
        }
        __syncthreads();
        float2* cT = reinterpret_cast<float2*>(b1);
        float si, ci;
        sincosf(W32A * (float)r, &si, &ci);
        const float2 stepi = make_float2(ci, -si);
        #pragma unroll
        for (int cc = c0; cc < c0 + 4; ++cc) {
            float2 wv = make_float2(1.f, 0.f), acc = make_float2(0.f, 0.f);
            for (int rr = 0; rr < 32; ++rr) {
                float kv = sk[KIDX(32*rr + cc)];
                acc.x = fmaf(kv, wv.x, acc.x);
                acc.y = fmaf(kv, wv.y, acc.y);
                wv = cmul2(wv, stepi);
            }
            float sp, cp;
            sincosf(W1KA * (float)(r * cc), &sp, &cp);
            cT[r*SF2 + cc] = cmul2(acc, make_float2(cp, -sp));
        }
        __syncthreads();   // all sk reads done; aA2 reusable after this point
        #pragma unroll
        for (int jj = 0; jj < 4; ++jj) {
            const int j = c0 + jj;
            float sj, cj;
            sincosf(W32A * (float)j, &sj, &cj);
            const float2 stepj = make_float2(cj, -sj);
            float2 wv = make_float2(1.f, 0.f), acc = make_float2(0.f, 0.f);
            for (int cc = 0; cc < 32; ++cc) {
                float2 tv = cT[r*SF2 + cc];
                acc.x = fmaf(tv.x, wv.x, fmaf(-tv.y, wv.y, acc.x));
                acc.y = fmaf(tv.x, wv.y, fmaf( tv.y, wv.x, acc.y));
                wv = cmul2(wv, stepj);
            }
            kfr[jj] = upk(pk2(acc.x, acc.y));   // keep bf16 rounding semantics
        }
    }

    // ---- prologue: stage first pass pair into aA2 (f32 complex) ----
    {
        const size_t be = ((size_t)(2*p0) * 1024 + h) * 1024;
        float4 ue = *reinterpret_cast<const float4*>(U + be + 4*t);
        float4 uo = *reinterpret_cast<const float4*>(U + be + 1048576 + 4*t);
        *reinterpret_cast<float4*>(&aA2[r*SF2 + c0]) =
            make_float4(rt_bf(ue.x), rt_bf(uo.x), rt_bf(ue.y), rt_bf(uo.y));
        *reinterpret_cast<float4*>(&aA2[r*SF2 + c0 + 2]) =
            make_float4(rt_bf(ue.z), rt_bf(uo.z), rt_bf(ue.w), rt_bf(uo.w));
    }

    const f32x2 scv = {SC1K, -SC1K};

    // ==== PASSES passes (2 b-tiles each), 2 barriers per pass ====
    for (int ii = 0; ii < PASSES; ++ii) {
        const int pass = p0 + ii;
        const size_t be = ((size_t)(2*pass) * 1024 + h) * 1024;

        __syncthreads();   // barrier A: aA2 + cF2 visible; b1 free

        // S1: X1[i][c] = sum_j F[i][j]*Z[j][c] ; * tw (= conj(twinv)*2^-10) ; -> b1
        {
            f32x2 A0={0,0}, A1={0,0}, A2={0,0}, A3={0,0};
            #pragma unroll 16
            for (int j = 0; j < 32; ++j) {
                float2 fv2 = cF2[r*SF2 + j];
                f32x2 fv = {fv2.x, fv2.y};
                float4 a01 = *reinterpret_cast<const float4*>(&aA2[j*SF2 + c0]);
                float4 a23 = *reinterpret_cast<const float4*>(&aA2[j*SF2 + c0 + 2]);
                vcmac(A0, fv, (f32x2){a01.x, a01.y});
                vcmac(A1, fv, (f32x2){a01.z, a01.w});
                vcmac(A2, fv, (f32x2){a23.x, a23.y});
                vcmac(A3, fv, (f32x2){a23.z, a23.w});
            }
            f32x2 x0 = vcmul(A0, twi[0] * scv);
            f32x2 x1 = vcmul(A1, twi[1] * scv);
            f32x2 x2 = vcmul(A2, twi[2] * scv);
            f32x2 x3 = vcmul(A3, twi[3] * scv);
            *reinterpret_cast<float4*>(&b1[r*SF2 + c0    ]) = make_float4(x0.x, x0.y, x1.x, x1.y);
            *reinterpret_cast<float4*>(&b1[r*SF2 + c0 + 2]) = make_float4(x2.x, x2.y, x3.x, x3.y);
        }

        // prefetch next pass's pair (latency hidden under S2+S3)
        float4 pe, po;
        if (ii < PASSES - 1) {
            const size_t nb = ((size_t)(2*pass + 2) * 1024 + h) * 1024;
            pe = *reinterpret_cast<const float4*>(U + nb + 4*t);
            po = *reinterpret_cast<const float4*>(U + nb + 1048576 + 4*t);
        }

        // S2: X2[i][m] = sum_c X1tw[i][c]*F[c][m] ; * kf ; in-place b1 (own rows)
        {
            f32x2 A0={0,0}, A1={0,0}, A2={0,0}, A3={0,0};
            #pragma unroll 16
            for (int c = 0; c < 32; ++c) {
                f32x2 xv = b1[r*SF2 + c];
                float4 f01 = *reinterpret_cast<const float4*>(&cF2[c*SF2 + c0]);
                float4 f23 = *reinterpret_cast<const float4*>(&cF2[c*SF2 + c0 + 2]);
                vcmac(A0, xv, (f32x2){f01.x, f01.y});
                vcmac(A1, xv, (f32x2){f01.z, f01.w});
                vcmac(A2, xv, (f32x2){f23.x, f23.y});
                vcmac(A3, xv, (f32x2){f23.z, f23.w});
            }
            f32x2 y0 = vcmul(A0, kfr[0]);
            f32x2 y1 = vcmul(A1, kfr[1]);
            f32x2 y2 = vcmul(A2, kfr[2]);
            f32x2 y3 = vcmul(A3, kfr[3]);
            *reinterpret_cast<float4*>(&b1[r*SF2 + c0    ]) = make_float4(y0.x, y0.y, y1.x, y1.y);
            *reinterpret_cast<float4*>(&b1[r*SF2 + c0 + 2]) = make_float4(y2.x, y2.y, y3.x, y3.y);
        }

        // S3: W[i][p] = sum_m Y[i][m]*conj(F[m][p]) ; * twinv ; in-place b1 (own rows)
        {
            f32x2 A0={0,0}, A1={0,0}, A2={0,0}, A3={0,0};
            #pragma unroll 16
            for (int m = 0; m < 32; ++m) {
                f32x2 yv = b1[r*SF2 + m];
                float4 g01 = *reinterpret_cast<const float4*>(&cF2[m*SF2 + c0]);
                float4 g23 = *reinterpret_cast<const float4*>(&cF2[m*SF2 + c0 + 2]);
                vcmacC(A0, yv, (f32x2){g01.x, g01.y});
                vcmacC(A1, yv, (f32x2){g01.z, g01.w});
                vcmacC(A2, yv, (f32x2){g23.x, g23.y});
                vcmacC(A3, yv, (f32x2){g23.z, g23.w});
            }
            f32x2 z0 = vcmul(A0, twi[0]);
            f32x2 z1 = vcmul(A1, twi[1]);
            f32x2 z2 = vcmul(A2, twi[2]);
            f32x2 z3 = vcmul(A3, twi[3]);
            *reinterpret_cast<float4*>(&b1[r*SF2 + c0    ]) = make_float4(z0.x, z0.y, z1.x, z1.y);
            *reinterpret_cast<float4*>(&b1[r*SF2 + c0 + 2]) = make_float4(z2.x, z2.y, z3.x, z3.y);
        }

        __syncthreads();   // barrier B: all Z rows ready; aA2 reads done

        // stage next pair (aA2 dead until next pass's S1, after barrier A)
        if (ii < PASSES - 1) {
            *reinterpret_cast<float4*>(&aA2[r*SF2 + c0]) =
                make_float4(rt_bf(pe.x), rt_bf(po.x), rt_bf(pe.y), rt_bf(po.y));
            *reinterpret_cast<float4*>(&aA2[r*SF2 + c0 + 2]) =
                make_float4(rt_bf(pe.z), rt_bf(po.z), rt_bf(pe.w), rt_bf(po.w));
        }

        // S4: O[q][p] = sum_i conj(F[q][i])*Z[i][p] ; Re -> tile 2p, Im -> tile 2p+1
        {
            f32x2 O0={0,0}, O1={0,0}, O2={0,0}, O3={0,0};
            #pragma unroll 16
            for (int i = 0; i < 32; ++i) {
                float2 gv2 = cF2[r*SF2 + i];
                f32x2 gv = {gv2.x, gv2.y};
                float4 p01 = *reinterpret_cast<const float4*>(&b1[i*SF2 + c0]);
                float4 p23 = *reinterpret_cast<const float4*>(&b1[i*SF2 + c0 + 2]);
                vcmacC(O0, (f32x2){p01.x, p01.y}, gv);
                vcmacC(O1, (f32x2){p01.z, p01.w}, gv);
                vcmacC(O2, (f32x2){p23.x, p23.y}, gv);
                vcmacC(O3, (f32x2){p23.z, p23.w}, gv);
            }
            *reinterpret_cast<float4*>(OUT + be + 4*t) =
                make_float4(O0.x, O1.x, O2.x, O3.x);
            *reinterpret_cast<float4*>(OUT + be + 1048576 + 4*t) =
                make_float4(O0.y, O1.y, O2.y, O3.y);
        }
    }
}

extern "C" void kernel_launch(void* const* d_in, const int* in_sizes, int n_in,
                              void* d_out, int out_size, void* d_ws, size_t ws_size,
                              hipStream_t stream) {
    const float* U = (const float*)d_in[0];
    const float* K = (const float*)d_in[1];
    float* OUT = (float*)d_out;

    if (ws_size >= (size_t)4 * 1024 * 1024) {
        unsigned int* kf = (unsigned int*)d_ws;
        kfft_pre9<<<dim3(1024), dim3(256), 0, stream>>>(K, kf);
        tkmon9<2, true><<<dim3(4096), dim3(256), 0, stream>>>(U, K, kf, OUT);
    } else {
        tkmon9<4, false><<<dim3(2048), dim3(256), 0, stream>>>(U, K, nullptr, OUT);
    }
}

// Round 20
// 124.783 us; speedup vs baseline: 2.6660x; 1.0600x over previous
//
#include <hip/hip_runtime.h>
#include <hip/hip_bf16.h>

typedef float f32x2 __attribute__((ext_vector_type(2)));

#define SP 36                      // float stride for SoA planes (144 B rows, 16B-aligned)
#define SF2 34                     // float2 stride for fallback CT scratch
#define KIDX(i) ((i) + ((i) >> 5)) // +1-per-32 padded f32 k-row addressing
#define W32A 0.19634954084936207f  // 2*pi/32
#define W1KA 0.006135923151542565f // 2*pi/1024
#define SC1K 0.0009765625f         // 2^-10 (exact)

#define VF __builtin_elementwise_fma

__device__ __forceinline__ unsigned short f2bf(float x) {
    union { __hip_bfloat16 h; unsigned short u; } cv;
    cv.h = __float2bfloat16(x);
    return cv.u;
}
__device__ __forceinline__ float bfb2f(unsigned short b) {
    union { unsigned int u; float f; } cv;
    cv.u = ((unsigned int)b) << 16;
    return cv.f;
}
__device__ __forceinline__ float rt_bf(float x) { return bfb2f(f2bf(x)); }
__device__ __forceinline__ unsigned int pk2(float re, float im) {
    return (unsigned int)f2bf(re) | ((unsigned int)f2bf(im) << 16);
}
__device__ __forceinline__ f32x2 upk(unsigned int p) {
    union { unsigned int u; float f; } a, b;
    a.u = p << 16;
    b.u = p & 0xFFFF0000u;
    return (f32x2){a.f, b.f};
}
__device__ __forceinline__ float2 cmul2(float2 a, float2 b) {
    return make_float2(a.x*b.x - a.y*b.y, a.x*b.y + a.y*b.x);
}

// ---------- standalone per-h k-FFT: KF[h*1024+i*32+j]=pack(k_hat[i+32j]) ----------
__global__ __launch_bounds__(256) void kfft_pre10(const float* __restrict__ K,
                                                  unsigned int* __restrict__ KF)
{
    __shared__ float sk[1056];
    __shared__ float2 cT[32*SF2];
    const int t = threadIdx.x, h = blockIdx.x;
    #pragma unroll
    for (int s = 0; s < 4; ++s) {
        int i = t + 256*s;
        sk[KIDX(i)] = K[(size_t)h*1024 + i];
    }
    __syncthreads();
    const int i0 = t >> 3, q0 = (t & 7) << 2;
    float si, ci;
    sincosf(W32A * (float)i0, &si, &ci);
    const float2 stepi = make_float2(ci, -si);
    #pragma unroll
    for (int cc = q0; cc < q0 + 4; ++cc) {
        float2 wv = make_float2(1.f, 0.f), acc = make_float2(0.f, 0.f);
        for (int rr = 0; rr < 32; ++rr) {
            float kv = sk[KIDX(32*rr + cc)];
            acc.x = fmaf(kv, wv.x, acc.x);
            acc.y = fmaf(kv, wv.y, acc.y);
            wv = cmul2(wv, stepi);
        }
        float sp, cp;
        sincosf(W1KA * (float)(i0 * cc), &sp, &cp);
        cT[i0*SF2 + cc] = cmul2(acc, make_float2(cp, -sp));
    }
    __syncthreads();
    #pragma unroll
    for (int j = q0; j < q0 + 4; ++j) {
        float sj, cj;
        sincosf(W32A * (float)j, &sj, &cj);
        const float2 stepj = make_float2(cj, -sj);
        float2 wv = make_float2(1.f, 0.f), acc = make_float2(0.f, 0.f);
        for (int cc = 0; cc < 32; ++cc) {
            float2 tv = cT[i0*SF2 + cc];
            acc.x = fmaf(tv.x, wv.x, fmaf(-tv.y, wv.y, acc.x));
            acc.y = fmaf(tv.x, wv.y, fmaf( tv.y, wv.x, acc.y));
            wv = cmul2(wv, stepj);
        }
        KF[(size_t)h*1024 + i0*32 + j] = pk2(acc.x, acc.y);
    }
}

// ---------- main fused monarch conv, SoA planes; PASSES pairs per block ----------
template<int PASSES, bool USEKF>
__global__ __launch_bounds__(256) void tkmon10(
    const float* __restrict__ U, const float* __restrict__ K,
    const unsigned int* __restrict__ KF, float* __restrict__ OUT)
{
    constexpr int SH = (PASSES == 2) ? 2 : 1;
    __shared__ __align__(16) float cFre[32*SP];    // F re (bf16-rounded, f32)
    __shared__ __align__(16) float cFim[32*SP];    // F im ; Finv = conj via signs
    __shared__ __align__(16) float aAbuf[2*32*SP]; // A re/im planes; sk in fallback
    __shared__ __align__(16) float b1buf[2*32*SP]; // stage re/im planes; CT scratch

    float* aAre = aAbuf;
    float* aAim = aAbuf + 32*SP;
    float* b1re = b1buf;
    float* b1im = b1buf + 32*SP;

    const int t  = threadIdx.x;
    const int h  = blockIdx.x >> SH;
    const int p0 = (blockIdx.x & ((1 << SH) - 1)) * PASSES;
    const int r  = t >> 3;
    const int c0 = (t & 7) << 2;

    // ---- F tables (SoA, bf16-rounded values) ----
    #pragma unroll
    for (int ii = 0; ii < 4; ++ii) {
        int idx = 4*t + ii;
        int rr = idx >> 5, cc = idx & 31;
        int m32 = (rr * cc) & 31;
        float s32, c32; sincosf((float)m32 * W32A, &s32, &c32);
        cFre[rr*SP + cc] = rt_bf(c32);
        cFim[rr*SP + cc] = rt_bf(-s32);
    }

    // ---- thread-invariant epilogue factors, column-pair packed registers ----
    float tre[4], tim[4];
    #pragma unroll
    for (int i = 0; i < 4; ++i) {
        int m1k = (r * (c0 + i)) & 1023;
        float s1k, c1k; sincosf((float)m1k * W1KA, &s1k, &c1k);
        tre[i] = rt_bf(c1k);
        tim[i] = rt_bf(s1k);
    }
    const f32x2 twire01 = {tre[0], tre[1]}, twire23 = {tre[2], tre[3]};
    const f32x2 twiim01 = {tim[0], tim[1]}, twiim23 = {tim[2], tim[3]};
    const f32x2 tw2re01 = twire01 * (f32x2){SC1K, SC1K};
    const f32x2 tw2re23 = twire23 * (f32x2){SC1K, SC1K};
    const f32x2 tw2im01 = twiim01 * (f32x2){-SC1K, -SC1K};
    const f32x2 tw2im23 = twiim23 * (f32x2){-SC1K, -SC1K};

    f32x2 kfre01, kfre23, kfim01, kfim23;
    if (USEKF) {
        uint4 kv = *reinterpret_cast<const uint4*>(&KF[(size_t)h*1024 + 4*t]);
        f32x2 k0 = upk(kv.x), k1 = upk(kv.y), k2 = upk(kv.z), k3 = upk(kv.w);
        kfre01 = (f32x2){k0.x, k1.x}; kfim01 = (f32x2){k0.y, k1.y};
        kfre23 = (f32x2){k2.x, k3.x}; kfim23 = (f32x2){k2.y, k3.y};
    } else {
        // in-block k-FFT; sk overlays aAbuf, cT overlays b1buf
        float* sk = aAbuf;
        #pragma unroll
        for (int s = 0; s < 4; ++s) {
            int i = t + 256*s;
            sk[KIDX(i)] = K[(size_t)h*1024 + i];
        }
        __syncthreads();
        float2* cT = reinterpret_cast<float2*>(b1buf);
        float si, ci;
        sincosf(W32A * (float)r, &si, &ci);
        const float2 stepi = make_float2(ci, -si);
        #pragma unroll
        for (int cc = c0; cc < c0 + 4; ++cc) {
            float2 wv = make_float2(1.f, 0.f), acc = make_float2(0.f, 0.f);
            for (int rr = 0; rr < 32; ++rr) {
                float kv = sk[KIDX(32*rr + cc)];
                acc.x = fmaf(kv, wv.x, acc.x);
                acc.y = fmaf(kv, wv.y, acc.y);
                wv = cmul2(wv, stepi);
            }
            float sp, cp;
            sincosf(W1KA * (float)(r * cc), &sp, &cp);
            cT[r*SF2 + cc] = cmul2(acc, make_float2(cp, -sp));
        }
        __syncthreads();   // all sk reads done; aAbuf reusable
        f32x2 kfr[4];
        #pragma unroll
        for (int jj = 0; jj < 4; ++jj) {
            const int j = c0 + jj;
            float sj, cj;
            sincosf(W32A * (float)j, &sj, &cj);
            const float2 stepj = make_float2(cj, -sj);
            float2 wv = make_float2(1.f, 0.f), acc = make_float2(0.f, 0.f);
            for (int cc = 0; cc < 32; ++cc) {
                float2 tv = cT[r*SF2 + cc];
                acc.x = fmaf(tv.x, wv.x, fmaf(-tv.y, wv.y, acc.x));
                acc.y = fmaf(tv.x, wv.y, fmaf( tv.y, wv.x, acc.y));
                wv = cmul2(wv, stepj);
            }
            kfr[jj] = upk(pk2(acc.x, acc.y));
        }
        kfre01 = (f32x2){kfr[0].x, kfr[1].x}; kfim01 = (f32x2){kfr[0].y, kfr[1].y};
        kfre23 = (f32x2){kfr[2].x, kfr[3].x}; kfim23 = (f32x2){kfr[2].y, kfr[3].y};
    }

    // ---- prologue: stage first pass pair into SoA planes ----
    {
        const size_t be = ((size_t)(2*p0) * 1024 + h) * 1024;
        float4 ue = *reinterpret_cast<const float4*>(U + be + 4*t);
        float4 uo = *reinterpret_cast<const float4*>(U + be + 1048576 + 4*t);
        *reinterpret_cast<float4*>(&aAre[r*SP + c0]) =
            make_float4(rt_bf(ue.x), rt_bf(ue.y), rt_bf(ue.z), rt_bf(ue.w));
        *reinterpret_cast<float4*>(&aAim[r*SP + c0]) =
            make_float4(rt_bf(uo.x), rt_bf(uo.y), rt_bf(uo.z), rt_bf(uo.w));
    }

    // ==== PASSES passes (2 b-tiles each), 2 barriers per pass ====
    for (int ii = 0; ii < PASSES; ++ii) {
        const int pass = p0 + ii;
        const size_t be = ((size_t)(2*pass) * 1024 + h) * 1024;

        __syncthreads();   // barrier A: aA planes + tables visible; b1 free

        // S1: X1[i][c] = sum_j F[i][j]*Z[j][c] ; * tw ; -> b1
        {
            f32x2 Ar01={0,0}, Ar23={0,0}, Ai01={0,0}, Ai23={0,0};
            #pragma unroll 16
            for (int j = 0; j < 32; ++j) {
                float sre = cFre[r*SP + j], sim = cFim[r*SP + j];
                f32x2 sreB = {sre, sre}, simB = {sim, sim};
                float4 vre = *reinterpret_cast<const float4*>(&aAre[j*SP + c0]);
                float4 vim = *reinterpret_cast<const float4*>(&aAim[j*SP + c0]);
                Ar01 = VF(sreB, ((f32x2){vre.x, vre.y}), Ar01);
                Ar01 = VF(-simB, ((f32x2){vim.x, vim.y}), Ar01);
                Ai01 = VF(sreB, ((f32x2){vim.x, vim.y}), Ai01);
                Ai01 = VF(simB, ((f32x2){vre.x, vre.y}), Ai01);
                Ar23 = VF(sreB, ((f32x2){vre.z, vre.w}), Ar23);
                Ar23 = VF(-simB, ((f32x2){vim.z, vim.w}), Ar23);
                Ai23 = VF(sreB, ((f32x2){vim.z, vim.w}), Ai23);
                Ai23 = VF(simB, ((f32x2){vre.z, vre.w}), Ai23);
            }
            f32x2 xre01 = VF(Ar01, tw2re01, -(Ai01 * tw2im01));
            f32x2 xim01 = VF(Ar01, tw2im01, Ai01 * tw2re01);
            f32x2 xre23 = VF(Ar23, tw2re23, -(Ai23 * tw2im23));
            f32x2 xim23 = VF(Ar23, tw2im23, Ai23 * tw2re23);
            *reinterpret_cast<float4*>(&b1re[r*SP + c0]) =
                make_float4(xre01.x, xre01.y, xre23.x, xre23.y);
            *reinterpret_cast<float4*>(&b1im[r*SP + c0]) =
                make_float4(xim01.x, xim01.y, xim23.x, xim23.y);
        }

        // prefetch next pass's pair (latency hidden under S2+S3)
        float4 pe, po;
        if (ii < PASSES - 1) {
            const size_t nb = ((size_t)(2*pass + 2) * 1024 + h) * 1024;
            pe = *reinterpret_cast<const float4*>(U + nb + 4*t);
            po = *reinterpret_cast<const float4*>(U + nb + 1048576 + 4*t);
        }

        // S2: X2[i][m] = sum_c X1tw[i][c]*F[c][m] ; * kf ; in-place b1 (own rows)
        {
            f32x2 Ar01={0,0}, Ar23={0,0}, Ai01={0,0}, Ai23={0,0};
            #pragma unroll 16
            for (int c = 0; c < 32; ++c) {
                float sre = b1re[r*SP + c], sim = b1im[r*SP + c];
                f32x2 sreB = {sre, sre}, simB = {sim, sim};
                float4 vre = *reinterpret_cast<const float4*>(&cFre[c*SP + c0]);
                float4 vim = *reinterpret_cast<const float4*>(&cFim[c*SP + c0]);
                Ar01 = VF(sreB, ((f32x2){vre.x, vre.y}), Ar01);
                Ar01 = VF(-simB, ((f32x2){vim.x, vim.y}), Ar01);
                Ai01 = VF(sreB, ((f32x2){vim.x, vim.y}), Ai01);
                Ai01 = VF(simB, ((f32x2){vre.x, vre.y}), Ai01);
                Ar23 = VF(sreB, ((f32x2){vre.z, vre.w}), Ar23);
                Ar23 = VF(-simB, ((f32x2){vim.z, vim.w}), Ar23);
                Ai23 = VF(sreB, ((f32x2){vim.z, vim.w}), Ai23);
                Ai23 = VF(simB, ((f32x2){vre.z, vre.w}), Ai23);
            }
            f32x2 yre01 = VF(Ar01, kfre01, -(Ai01 * kfim01));
            f32x2 yim01 = VF(Ar01, kfim01, Ai01 * kfre01);
            f32x2 yre23 = VF(Ar23, kfre23, -(Ai23 * kfim23));
            f32x2 yim23 = VF(Ar23, kfim23, Ai23 * kfre23);
            *reinterpret_cast<float4*>(&b1re[r*SP + c0]) =
                make_float4(yre01.x, yre01.y, yre23.x, yre23.y);
            *reinterpret_cast<float4*>(&b1im[r*SP + c0]) =
                make_float4(yim01.x, yim01.y, yim23.x, yim23.y);
        }

        // S3: W[i][p] = sum_m Y[i][m]*conj(F[m][p]) ; * twinv ; in-place b1 (own rows)
        {
            f32x2 Ar01={0,0}, Ar23={0,0}, Ai01={0,0}, Ai23={0,0};
            #pragma unroll 16
            for (int m = 0; m < 32; ++m) {
                float sre = b1re[r*SP + m], sim = b1im[r*SP + m];
                f32x2 sreB = {sre, sre}, simB = {sim, sim};
                float4 vre = *reinterpret_cast<const float4*>(&cFre[m*SP + c0]);
                float4 vim = *reinterpret_cast<const float4*>(&cFim[m*SP + c0]);
                Ar01 = VF(((f32x2){vre.x, vre.y}), sreB, Ar01);
                Ar01 = VF(simB, ((f32x2){vim.x, vim.y}), Ar01);
                Ai01 = VF(((f32x2){vre.x, vre.y}), simB, Ai01);
                Ai01 = VF(-sreB, ((f32x2){vim.x, vim.y}), Ai01);
                Ar23 = VF(((f32x2){vre.z, vre.w}), sreB, Ar23);
                Ar23 = VF(simB, ((f32x2){vim.z, vim.w}), Ar23);
                Ai23 = VF(((f32x2){vre.z, vre.w}), simB, Ai23);
                Ai23 = VF(-sreB, ((f32x2){vim.z, vim.w}), Ai23);
            }
            f32x2 zre01 = VF(Ar01, twire01, -(Ai01 * twiim01));
            f32x2 zim01 = VF(Ar01, twiim01, Ai01 * twire01);
            f32x2 zre23 = VF(Ar23, twire23, -(Ai23 * twiim23));
            f32x2 zim23 = VF(Ar23, twiim23, Ai23 * twire23);
            *reinterpret_cast<float4*>(&b1re[r*SP + c0]) =
                make_float4(zre01.x, zre01.y, zre23.x, zre23.y);
            *reinterpret_cast<float4*>(&b1im[r*SP + c0]) =
                make_float4(zim01.x, zim01.y, zim23.x, zim23.y);
        }

        __syncthreads();   // barrier B: all Z rows ready; aA reads done

        // stage next pair (aA dead until next pass's S1, after barrier A)
        if (ii < PASSES - 1) {
            *reinterpret_cast<float4*>(&aAre[r*SP + c0]) =
                make_float4(rt_bf(pe.x), rt_bf(pe.y), rt_bf(pe.z), rt_bf(pe.w));
            *reinterpret_cast<float4*>(&aAim[r*SP + c0]) =
                make_float4(rt_bf(po.x), rt_bf(po.y), rt_bf(po.z), rt_bf(po.w));
        }

        // S4: O[q][p] = sum_i conj(F[q][i])*Z[i][p] ; Re -> tile 2p, Im -> tile 2p+1
        {
            f32x2 Or01={0,0}, Or23={0,0}, Oi01={0,0}, Oi23={0,0};
            #pragma unroll 16
            for (int i = 0; i < 32; ++i) {
                float sre = cFre[r*SP + i], sim = cFim[r*SP + i];
                f32x2 sreB = {sre, sre}, simB = {sim, sim};
                float4 vre = *reinterpret_cast<const float4*>(&b1re[i*SP + c0]);
                float4 vim = *reinterpret_cast<const float4*>(&b1im[i*SP + c0]);
                Or01 = VF(sreB, ((f32x2){vre.x, vre.y}), Or01);
                Or01 = VF(((f32x2){vim.x, vim.y}), simB, Or01);
                Oi01 = VF(sreB, ((f32x2){vim.x, vim.y}), Oi01);
                Oi01 = VF(-((f32x2){vre.x, vre.y}), simB, Oi01);
                Or23 = VF(sreB, ((f32x2){vre.z, vre.w}), Or23);
                Or23 = VF(((f32x2){vim.z, vim.w}), simB, Or23);
                Oi23 = VF(sreB, ((f32x2){vim.z, vim.w}), Oi23);
                Oi23 = VF(-((f32x2){vre.z, vre.w}), simB, Oi23);
            }
            *reinterpret_cast<float4*>(OUT + be + 4*t) =
                make_float4(Or01.x, Or01.y, Or23.x, Or23.y);
            *reinterpret_cast<float4*>(OUT + be + 1048576 + 4*t) =
                make_float4(Oi01.x, Oi01.y, Oi23.x, Oi23.y);
        }
    }
}

extern "C" void kernel_launch(void* const* d_in, const int* in_sizes, int n_in,
                              void* d_out, int out_size, void* d_ws, size_t ws_size,
                              hipStream_t stream) {
    const float* U = (const float*)d_in[0];
    const float* K = (const float*)d_in[1];
    float* OUT = (float*)d_out;

    if (ws_size >= (size_t)4 * 1024 * 1024) {
        unsigned int* kf = (unsigned int*)d_ws;
        kfft_pre10<<<dim3(1024), dim3(256), 0, stream>>>(K, kf);
        tkmon10<2, true><<<dim3(4096), dim3(256), 0, stream>>>(U, K, kf, OUT);
    } else {
        tkmon10<4, false><<<dim3(2048), dim3(256), 0, stream>>>(U, K, nullptr, OUT);
    }
}